// Round 4
// baseline (613.069 us; speedup 1.0000x reference)
//
#include <hip/hip_runtime.h>
#include <math.h>

#define B_ 4
#define N_ 4096
#define E_ 131072
#define ET_ (E_ + N_)   /* 135168 edges incl. self-loops */
#define H_ 4
#define HD_ 256
#define C_ 6

typedef short  s16x8  __attribute__((ext_vector_type(8)));
typedef __bf16 bf16x8 __attribute__((ext_vector_type(8)));
typedef float  f32x4  __attribute__((ext_vector_type(4)));

__device__ inline unsigned short f2bf(float f){
  unsigned u = __builtin_bit_cast(unsigned, f);
  return (unsigned short)((u + 0x7FFFu + ((u >> 16) & 1u)) >> 16);
}
__device__ inline float bf2f(unsigned short s){
  unsigned u = ((unsigned)s) << 16;
  return __builtin_bit_cast(float, u);
}
__device__ inline void split2(float f, short& hi, short& lo){
  unsigned short h = f2bf(f);
  hi = (short)h;
  lo = (short)f2bf(f - bf2f(h));
}
__device__ inline f32x4 mfma_bf16(s16x8 a, s16x8 b, f32x4 c){
  return __builtin_amdgcn_mfma_f32_16x16x32_bf16(
      __builtin_bit_cast(bf16x8, a), __builtin_bit_cast(bf16x8, b), c, 0, 0, 0);
}

// ---------------- CSR build (counting sort by dst) ----------------
__global__ void k_count(const int* __restrict__ ei, int* __restrict__ counts){
  int idx = blockIdx.x*256 + threadIdx.x;
  if (idx >= B_*ET_) return;
  int b = idx / ET_, i = idx - b*ET_;
  int dst = (i < E_) ? ei[b*2*E_ + E_ + i] : (i - E_);
  atomicAdd(&counts[b*N_ + dst], 1);
}

__global__ void k_scan(const int* __restrict__ counts, int* __restrict__ offs){
  __shared__ int lds[1024];
  int b = blockIdx.x, t = threadIdx.x;
  int c[4]; int tot = 0;
  #pragma unroll
  for (int j=0;j<4;j++){ c[j] = counts[b*N_ + t*4 + j]; tot += c[j]; }
  lds[t] = tot; __syncthreads();
  for (int off=1; off<1024; off<<=1){
    int u = (t>=off) ? lds[t-off] : 0;
    __syncthreads();
    lds[t] += u;
    __syncthreads();
  }
  int excl = lds[t] - tot;
  int o = excl;
  #pragma unroll
  for (int j=0;j<4;j++){ offs[b*(N_+1) + t*4 + j] = o; o += c[j]; }
  if (t==1023) offs[b*(N_+1) + N_] = o;
}

__global__ void k_scatter(const int* __restrict__ ei, const int* __restrict__ offs,
                          int* __restrict__ cursor, unsigned short* __restrict__ srcs){
  int idx = blockIdx.x*256 + threadIdx.x;
  if (idx >= B_*ET_) return;
  int b = idx / ET_, i = idx - b*ET_;
  int src, dst;
  if (i < E_){ src = ei[b*2*E_ + i]; dst = ei[b*2*E_ + E_ + i]; }
  else { src = i - E_; dst = src; }
  int pos = offs[b*(N_+1) + dst] + atomicAdd(&cursor[b*N_ + dst], 1);
  srcs[b*ET_ + pos] = (unsigned short)src;
}

// split + transpose W[K,NC] -> Wt[NC,K] (hi,lo)
__global__ void k_splitT(const float* __restrict__ w, short* __restrict__ hit,
                         short* __restrict__ lot, int K, int NC){
  int idx = blockIdx.x*256 + threadIdx.x;
  if (idx >= K*NC) return;
  int nn = idx / K, kk = idx - nn*K;
  float f = w[(size_t)kk*NC + nn];
  short h, l; split2(f, h, l);
  hit[idx] = h; lot[idx] = l;
}

// ---------------- split-bf16 MFMA GEMM: O[M,NC] = A[M,K] @ W[K,NC] ----------------
// A: either fp32 [M,K] (AFP32, split in staging) or pre-split Ah/Al [M,K].
// W: pre-split Bh/Bl [NC,K] (transposed). BM=BN=64, BK=32, 4 waves (2x2 of 32x32).
template<int K, bool AFP32>
__global__ __launch_bounds__(256) void k_mfma(const float* __restrict__ Af,
    const short* __restrict__ Ah, const short* __restrict__ Al,
    const short* __restrict__ Bh, const short* __restrict__ Bl,
    float* __restrict__ O, int NC){
  __shared__ short tAh[64][32], tAl[64][32], tBh[64][32], tBl[64][32];
  int t = threadIdx.x;
  int m0 = blockIdx.x*64, n0 = blockIdx.y*64;
  // staging role: thread t covers row r (0..63), 16B chunk c (0..3) of the 64x32 tile
  int r = t >> 2, c = t & 3;
  int cs = (c ^ ((r >> 1) & 3)) * 8;     // XOR-swizzled chunk (in shorts)
  // compute role
  int w = t >> 6, l = t & 63;
  int wr = w >> 1, wc = w & 1, g = l >> 4, li = l & 15;
  int rA = wr*32 + li, rB = wc*32 + li;
  int cA = (g ^ ((rA >> 1) & 3)) * 8;    // same swizzle applies to rA and rA+16
  int cB = (g ^ ((rB >> 1) & 3)) * 8;
  f32x4 z = {0.f,0.f,0.f,0.f};
  f32x4 acc00=z, acc01=z, acc10=z, acc11=z;

  s16x8 vah, vaL, vbh, vbl;
  auto loadSlice = [&](int k0){
    if constexpr (AFP32){
      const float* ap = &Af[(size_t)(m0+r)*K + k0 + c*8];
      float4 f0 = *reinterpret_cast<const float4*>(ap);
      float4 f1 = *reinterpret_cast<const float4*>(ap+4);
      float fv[8] = {f0.x,f0.y,f0.z,f0.w,f1.x,f1.y,f1.z,f1.w};
      #pragma unroll
      for (int j=0;j<8;j++){ short hh,ll; split2(fv[j],hh,ll); vah[j]=hh; vaL[j]=ll; }
    } else {
      vah = *reinterpret_cast<const s16x8*>(&Ah[(size_t)(m0+r)*K + k0 + c*8]);
      vaL = *reinterpret_cast<const s16x8*>(&Al[(size_t)(m0+r)*K + k0 + c*8]);
    }
    vbh = *reinterpret_cast<const s16x8*>(&Bh[(size_t)(n0+r)*K + k0 + c*8]);
    vbl = *reinterpret_cast<const s16x8*>(&Bl[(size_t)(n0+r)*K + k0 + c*8]);
  };

  loadSlice(0);
  for (int k0 = 0; k0 < K; k0 += 32){
    __syncthreads();                     // previous iteration's frag reads done
    *reinterpret_cast<s16x8*>(&tAh[r][cs]) = vah;
    *reinterpret_cast<s16x8*>(&tAl[r][cs]) = vaL;
    *reinterpret_cast<s16x8*>(&tBh[r][cs]) = vbh;
    *reinterpret_cast<s16x8*>(&tBl[r][cs]) = vbl;
    __syncthreads();
    if (k0 + 32 < K) loadSlice(k0 + 32); // lands during MFMAs
    s16x8 a0h = *reinterpret_cast<const s16x8*>(&tAh[rA   ][cA]);
    s16x8 a1h = *reinterpret_cast<const s16x8*>(&tAh[rA+16][cA]);
    s16x8 a0l = *reinterpret_cast<const s16x8*>(&tAl[rA   ][cA]);
    s16x8 a1l = *reinterpret_cast<const s16x8*>(&tAl[rA+16][cA]);
    s16x8 b0h = *reinterpret_cast<const s16x8*>(&tBh[rB   ][cB]);
    s16x8 b1h = *reinterpret_cast<const s16x8*>(&tBh[rB+16][cB]);
    s16x8 b0l = *reinterpret_cast<const s16x8*>(&tBl[rB   ][cB]);
    s16x8 b1l = *reinterpret_cast<const s16x8*>(&tBl[rB+16][cB]);
    acc00 = mfma_bf16(a0h, b0h, acc00);
    acc00 = mfma_bf16(a0h, b0l, acc00);
    acc00 = mfma_bf16(a0l, b0h, acc00);
    acc01 = mfma_bf16(a0h, b1h, acc01);
    acc01 = mfma_bf16(a0h, b1l, acc01);
    acc01 = mfma_bf16(a0l, b1h, acc01);
    acc10 = mfma_bf16(a1h, b0h, acc10);
    acc10 = mfma_bf16(a1h, b0l, acc10);
    acc10 = mfma_bf16(a1l, b0h, acc10);
    acc11 = mfma_bf16(a1h, b1h, acc11);
    acc11 = mfma_bf16(a1h, b1l, acc11);
    acc11 = mfma_bf16(a1l, b1h, acc11);
  }
  // C/D layout (HW-verified): col = lane&15, row = 4*(lane>>4) + reg
  f32x4 accs[2][2] = {{acc00, acc01},{acc10, acc11}};
  #pragma unroll
  for (int mi=0; mi<2; mi++)
    #pragma unroll
    for (int ni=0; ni<2; ni++){
      int row = m0 + wr*32 + mi*16 + 4*g;
      int col = n0 + wc*32 + ni*16 + li;
      #pragma unroll
      for (int j=0; j<4; j++)
        O[(size_t)(row+j)*NC + col] = accs[mi][ni][j];
    }
}

// ---------------- per-node attention coefficients a_s, a_d ----------------
template<int HD, int H>
__global__ void k_attn(const float* __restrict__ h, const float* __restrict__ atts,
                       const float* __restrict__ attd, float* __restrict__ a_s,
                       float* __restrict__ a_d){
  int n = blockIdx.x; int t = threadIdx.x;
  float v = h[(size_t)n*HD + t];
  float ps = v*atts[t], pd = v*attd[t];
  #pragma unroll
  for (int m=32;m>=1;m>>=1){ ps += __shfl_xor(ps,m,64); pd += __shfl_xor(pd,m,64); }
  if ((t&63)==0){ int head = t>>6; a_s[n*H + head]=ps; a_d[n*H + head]=pd; }
}

// ---------------- pull-mode edge-softmax aggregation ----------------
template<int HD, int H, bool ELU, bool SPLIT>
__global__ void k_aggr(const float* __restrict__ h, const float* __restrict__ a_s,
                       const float* __restrict__ a_d, const unsigned short* __restrict__ srcs,
                       const int* __restrict__ offs, const float* __restrict__ bias,
                       float* __restrict__ outf, short* __restrict__ outh,
                       short* __restrict__ outl){
  int ng = blockIdx.x;             // b*N + n
  int b = ng >> 12, n = ng & (N_-1);
  int t = threadIdx.x;
  int head = t >> 6;
  int st = offs[b*(N_+1)+n], en = offs[b*(N_+1)+n+1];
  float adv = a_d[ng*H + head];
  float acc = 0.f, psum = 0.f;
  const unsigned short* sp = &srcs[(size_t)b*ET_];
  const float* hb  = &h[(size_t)b*N_*HD];
  const float* asb = &a_s[(size_t)b*N_*H];
  for (int i=st;i<en;i++){
    int s = sp[i];
    float e = asb[s*H + head] + adv;
    e = e > 0.f ? e : 0.2f*e;
    float p = __expf(e);
    acc = fmaf(p, hb[(size_t)s*HD + t], acc);
    psum += p;
  }
  float val = acc/(psum + 1e-16f) + bias[t];
  if (ELU) val = val > 0.f ? val : expm1f(val);
  size_t idx = (size_t)ng*HD + t;
  if (SPLIT){ short hh, ll; split2(val, hh, ll); outh[idx]=hh; outl[idx]=ll; }
  else outf[idx] = val;
}

// ---------------- node-mean reduction ----------------
__global__ void k_reduce(const float* __restrict__ x3, float* __restrict__ embed){
  __shared__ float red[256];
  int bid = blockIdx.x; int b = bid>>4, chunk = bid & 15;
  int t = threadIdx.x; int col = t & 63, q = t>>6;
  float s = 0.f;
  int r0 = chunk*256 + q*64;
  const float* p = &x3[((size_t)b*N_ + r0)*64 + col];
  for (int j=0;j<64;j++) s += p[(size_t)j*64];
  red[t]=s; __syncthreads();
  if (t<64){
    float v = red[t]+red[t+64]+red[t+128]+red[t+192];
    atomicAdd(&embed[b*64+t], v);
  }
}

// ---------------- classifier + log_softmax + loss + argmax ----------------
__global__ void k_final(const float* __restrict__ embed, const float* __restrict__ Wc,
                        const float* __restrict__ bc, const int* __restrict__ labels,
                        float* __restrict__ out){
  __shared__ float lg[B_][C_];
  __shared__ float lossv[B_];
  int t = threadIdx.x;
  if (t < B_*C_){
    int b = t / C_, c = t - b*C_;
    float s = 0.f;
    for (int k=0;k<64;k++) s += embed[b*64+k]*Wc[k*C_+c];
    lg[b][c] = s*(1.0f/N_) + bc[c];
  }
  __syncthreads();
  if (t < B_){
    int b = t;
    float mx = lg[b][0]; int pred = 0;
    for (int c=1;c<C_;c++) if (lg[b][c] > mx){ mx = lg[b][c]; pred = c; }
    float se = 0.f;
    for (int c=0;c<C_;c++) se += expf(lg[b][c]-mx);
    float lse = mx + logf(se);
    int lab = labels[b];
    lossv[b] = lse - lg[b][lab];
    out[b]      = (float)pred;
    out[B_+b]   = (float)lab;
  }
  __syncthreads();
  if (t==0) out[8] = 0.25f*(lossv[0]+lossv[1]+lossv[2]+lossv[3]);
}

extern "C" void kernel_launch(void* const* d_in, const int* in_sizes, int n_in,
                              void* d_out, int out_size, void* d_ws, size_t ws_size,
                              hipStream_t stream){
  const float* x0     = (const float*)d_in[0];
  const int*   labels = (const int*)d_in[1];
  const int*   ei     = (const int*)d_in[2];
  const float* W1=(const float*)d_in[3],  *as1=(const float*)d_in[4],
             *ad1=(const float*)d_in[5],  *b1 =(const float*)d_in[6];
  const float* W2=(const float*)d_in[7],  *as2=(const float*)d_in[8],
             *ad2=(const float*)d_in[9],  *b2 =(const float*)d_in[10];
  const float* W3=(const float*)d_in[11], *as3=(const float*)d_in[12],
             *ad3=(const float*)d_in[13], *b3 =(const float*)d_in[14];
  const float* Wc=(const float*)d_in[15], *bc =(const float*)d_in[16];
  float* out = (float*)d_out;

  char* ws = (char*)d_ws;
  size_t off = 0;
  auto alloc = [&](size_t bytes)->void*{ void* p = ws + off; off += (bytes + 255) & ~(size_t)255; return p; };
  float* hbuf   = (float*)alloc((size_t)B_*N_*HD_*4);    // GEMM outputs [16384,256]
  float* xcur3  = hbuf + (size_t)B_*N_*64;               // alias: layer-3 aggr out in hbuf tail
  float* a_s    = (float*)alloc((size_t)B_*N_*H_*4);
  float* a_d    = (float*)alloc((size_t)B_*N_*H_*4);
  int*   counts = (int*)alloc((size_t)B_*N_*4);
  int*   offs   = (int*)alloc((size_t)B_*(N_+1)*4);
  int*   cursor = (int*)alloc((size_t)B_*N_*4);
  unsigned short* srcs = (unsigned short*)alloc((size_t)B_*ET_*2);
  float* embed  = (float*)alloc((size_t)B_*64*4);
  short* Ah     = (short*)alloc((size_t)B_*N_*HD_*2);    // split aggr out (layers 2-3 A)
  short* Al     = (short*)alloc((size_t)B_*N_*HD_*2);
  short* Wht    = (short*)alloc((size_t)768*256*2);      // split W^T (max)
  short* Wlt    = (short*)alloc((size_t)768*256*2);

  hipMemsetAsync(counts, 0, (size_t)B_*N_*4, stream);
  hipMemsetAsync(cursor, 0, (size_t)B_*N_*4, stream);
  hipMemsetAsync(embed,  0, (size_t)B_*64*4, stream);

  int nb = (B_*ET_ + 255)/256;
  k_count  <<<nb, 256, 0, stream>>>(ei, counts);
  k_scan   <<<B_, 1024, 0, stream>>>(counts, offs);
  k_scatter<<<nb, 256, 0, stream>>>(ei, offs, cursor, srcs);

  // ---- layer 1: 768 -> 4x64, concat, elu (A = x0 fp32, split in staging) ----
  {
    k_splitT<<<(768*256+255)/256, 256, 0, stream>>>(W1, Wht, Wlt, 768, 256);
    k_mfma<768,true><<<dim3(B_*N_/64, 4), 256, 0, stream>>>(x0, nullptr, nullptr,
                                                            Wht, Wlt, hbuf, 256);
    k_attn<256,4><<<B_*N_, 256, 0, stream>>>(hbuf, as1, ad1, a_s, a_d);
    k_aggr<256,4,true,true><<<B_*N_, 256, 0, stream>>>(hbuf, a_s, a_d, srcs, offs, b1,
                                                       nullptr, Ah, Al);
  }
  // ---- layer 2: 256 -> 4x64, concat, elu ----
  {
    k_splitT<<<(256*256+255)/256, 256, 0, stream>>>(W2, Wht, Wlt, 256, 256);
    k_mfma<256,false><<<dim3(B_*N_/64, 4), 256, 0, stream>>>(nullptr, Ah, Al,
                                                             Wht, Wlt, hbuf, 256);
    k_attn<256,4><<<B_*N_, 256, 0, stream>>>(hbuf, as2, ad2, a_s, a_d);
    k_aggr<256,4,true,true><<<B_*N_, 256, 0, stream>>>(hbuf, a_s, a_d, srcs, offs, b2,
                                                       nullptr, Ah, Al);
  }
  // ---- layer 3: 256 -> 64, 1 head, mean(=identity), no elu ----
  {
    k_splitT<<<(256*64+255)/256, 256, 0, stream>>>(W3, Wht, Wlt, 256, 64);
    k_mfma<256,false><<<dim3(B_*N_/64, 1), 256, 0, stream>>>(nullptr, Ah, Al,
                                                             Wht, Wlt, hbuf, 64);
    k_attn<64,1><<<B_*N_, 64, 0, stream>>>(hbuf, as3, ad3, a_s, a_d);
    k_aggr<64,1,false,false><<<B_*N_, 64, 0, stream>>>(hbuf, a_s, a_d, srcs, offs, b3,
                                                       xcur3, nullptr, nullptr);
  }

  k_reduce<<<B_*16, 256, 0, stream>>>(xcur3, embed);
  k_final <<<1, 64, 0, stream>>>(embed, Wc, bc, labels, out);
}

// Round 5
// 396.197 us; speedup vs baseline: 1.5474x; 1.5474x over previous
//
#include <hip/hip_runtime.h>
#include <math.h>

#define B_ 4
#define N_ 4096
#define E_ 131072
#define ET_ (E_ + N_)   /* 135168 edges incl. self-loops */
#define H_ 4
#define HD_ 256
#define C_ 6

typedef short  s16x8  __attribute__((ext_vector_type(8)));
typedef __bf16 bf16x8 __attribute__((ext_vector_type(8)));
typedef float  f32x4  __attribute__((ext_vector_type(4)));

__device__ inline unsigned short f2bf(float f){
  unsigned u = __builtin_bit_cast(unsigned, f);
  return (unsigned short)((u + 0x7FFFu + ((u >> 16) & 1u)) >> 16);
}
__device__ inline float bf2f(unsigned short s){
  unsigned u = ((unsigned)s) << 16;
  return __builtin_bit_cast(float, u);
}
__device__ inline void split2(float f, short& hi, short& lo){
  unsigned short h = f2bf(f);
  hi = (short)h;
  lo = (short)f2bf(f - bf2f(h));
}
__device__ inline f32x4 mfma_bf16(s16x8 a, s16x8 b, f32x4 c){
  return __builtin_amdgcn_mfma_f32_16x16x32_bf16(
      __builtin_bit_cast(bf16x8, a), __builtin_bit_cast(bf16x8, b), c, 0, 0, 0);
}

// ---------------- CSR build (counting sort by dst) ----------------
__global__ void k_count(const int* __restrict__ ei, int* __restrict__ counts){
  int idx = blockIdx.x*256 + threadIdx.x;
  if (idx >= B_*ET_) return;
  int b = idx / ET_, i = idx - b*ET_;
  int dst = (i < E_) ? ei[b*2*E_ + E_ + i] : (i - E_);
  atomicAdd(&counts[b*N_ + dst], 1);
}

__global__ void k_scan(const int* __restrict__ counts, int* __restrict__ offs){
  __shared__ int lds[1024];
  int b = blockIdx.x, t = threadIdx.x;
  int c[4]; int tot = 0;
  #pragma unroll
  for (int j=0;j<4;j++){ c[j] = counts[b*N_ + t*4 + j]; tot += c[j]; }
  lds[t] = tot; __syncthreads();
  for (int off=1; off<1024; off<<=1){
    int u = (t>=off) ? lds[t-off] : 0;
    __syncthreads();
    lds[t] += u;
    __syncthreads();
  }
  int excl = lds[t] - tot;
  int o = excl;
  #pragma unroll
  for (int j=0;j<4;j++){ offs[b*(N_+1) + t*4 + j] = o; o += c[j]; }
  if (t==1023) offs[b*(N_+1) + N_] = o;
}

__global__ void k_scatter(const int* __restrict__ ei, const int* __restrict__ offs,
                          int* __restrict__ cursor, unsigned short* __restrict__ srcs){
  int idx = blockIdx.x*256 + threadIdx.x;
  if (idx >= B_*ET_) return;
  int b = idx / ET_, i = idx - b*ET_;
  int src, dst;
  if (i < E_){ src = ei[b*2*E_ + i]; dst = ei[b*2*E_ + E_ + i]; }
  else { src = i - E_; dst = src; }
  int pos = offs[b*(N_+1) + dst] + atomicAdd(&cursor[b*N_ + dst], 1);
  srcs[b*ET_ + pos] = (unsigned short)src;
}

// split + transpose W[K,NC] -> Wt[NC,K] (hi,lo)
__global__ void k_splitT(const float* __restrict__ w, short* __restrict__ hit,
                         short* __restrict__ lot, int K, int NC){
  int idx = blockIdx.x*256 + threadIdx.x;
  if (idx >= K*NC) return;
  int nn = idx / K, kk = idx - nn*K;
  float f = w[(size_t)kk*NC + nn];
  short h, l; split2(f, h, l);
  hit[idx] = h; lot[idx] = l;
}

// ---------------- split-bf16 MFMA GEMM: O[M,NC] = A[M,K] @ W[K,NC] ----------------
// A: either fp32 [M,K] (AFP32, split in staging) or pre-split Ah/Al [M,K].
// W: pre-split Bh/Bl [NC,K] (transposed). BM=BN=64, BK=32, 4 waves (2x2 of 32x32).
template<int K, bool AFP32>
__global__ __launch_bounds__(256) void k_mfma(const float* __restrict__ Af,
    const short* __restrict__ Ah, const short* __restrict__ Al,
    const short* __restrict__ Bh, const short* __restrict__ Bl,
    float* __restrict__ O, int NC){
  __shared__ short tAh[64][32], tAl[64][32], tBh[64][32], tBl[64][32];
  int t = threadIdx.x;
  int m0 = blockIdx.x*64, n0 = blockIdx.y*64;
  // staging role: thread t covers row r (0..63), 16B chunk c (0..3) of the 64x32 tile
  int r = t >> 2, c = t & 3;
  int cs = (c ^ ((r >> 1) & 3)) * 8;     // XOR-swizzled chunk (in shorts)
  // compute role
  int w = t >> 6, l = t & 63;
  int wr = w >> 1, wc = w & 1, g = l >> 4, li = l & 15;
  int rA = wr*32 + li, rB = wc*32 + li;
  int cA = (g ^ ((rA >> 1) & 3)) * 8;    // same swizzle applies to rA and rA+16
  int cB = (g ^ ((rB >> 1) & 3)) * 8;
  f32x4 z = {0.f,0.f,0.f,0.f};
  f32x4 acc00=z, acc01=z, acc10=z, acc11=z;

  s16x8 vah, vaL, vbh, vbl;
  auto loadSlice = [&](int k0){
    if constexpr (AFP32){
      const float* ap = &Af[(size_t)(m0+r)*K + k0 + c*8];
      float4 f0 = *reinterpret_cast<const float4*>(ap);
      float4 f1 = *reinterpret_cast<const float4*>(ap+4);
      float fv[8] = {f0.x,f0.y,f0.z,f0.w,f1.x,f1.y,f1.z,f1.w};
      #pragma unroll
      for (int j=0;j<8;j++){ short hh,ll; split2(fv[j],hh,ll); vah[j]=hh; vaL[j]=ll; }
    } else {
      vah = *reinterpret_cast<const s16x8*>(&Ah[(size_t)(m0+r)*K + k0 + c*8]);
      vaL = *reinterpret_cast<const s16x8*>(&Al[(size_t)(m0+r)*K + k0 + c*8]);
    }
    vbh = *reinterpret_cast<const s16x8*>(&Bh[(size_t)(n0+r)*K + k0 + c*8]);
    vbl = *reinterpret_cast<const s16x8*>(&Bl[(size_t)(n0+r)*K + k0 + c*8]);
  };

  loadSlice(0);
  for (int k0 = 0; k0 < K; k0 += 32){
    __syncthreads();                     // previous iteration's frag reads done
    *reinterpret_cast<s16x8*>(&tAh[r][cs]) = vah;
    *reinterpret_cast<s16x8*>(&tAl[r][cs]) = vaL;
    *reinterpret_cast<s16x8*>(&tBh[r][cs]) = vbh;
    *reinterpret_cast<s16x8*>(&tBl[r][cs]) = vbl;
    __syncthreads();
    if (k0 + 32 < K) loadSlice(k0 + 32); // lands during MFMAs
    s16x8 a0h = *reinterpret_cast<const s16x8*>(&tAh[rA   ][cA]);
    s16x8 a1h = *reinterpret_cast<const s16x8*>(&tAh[rA+16][cA]);
    s16x8 a0l = *reinterpret_cast<const s16x8*>(&tAl[rA   ][cA]);
    s16x8 a1l = *reinterpret_cast<const s16x8*>(&tAl[rA+16][cA]);
    s16x8 b0h = *reinterpret_cast<const s16x8*>(&tBh[rB   ][cB]);
    s16x8 b1h = *reinterpret_cast<const s16x8*>(&tBh[rB+16][cB]);
    s16x8 b0l = *reinterpret_cast<const s16x8*>(&tBl[rB   ][cB]);
    s16x8 b1l = *reinterpret_cast<const s16x8*>(&tBl[rB+16][cB]);
    acc00 = mfma_bf16(a0h, b0h, acc00);
    acc00 = mfma_bf16(a0h, b0l, acc00);
    acc00 = mfma_bf16(a0l, b0h, acc00);
    acc01 = mfma_bf16(a0h, b1h, acc01);
    acc01 = mfma_bf16(a0h, b1l, acc01);
    acc01 = mfma_bf16(a0l, b1h, acc01);
    acc10 = mfma_bf16(a1h, b0h, acc10);
    acc10 = mfma_bf16(a1h, b0l, acc10);
    acc10 = mfma_bf16(a1l, b0h, acc10);
    acc11 = mfma_bf16(a1h, b1h, acc11);
    acc11 = mfma_bf16(a1h, b1l, acc11);
    acc11 = mfma_bf16(a1l, b1h, acc11);
  }
  // C/D layout (HW-verified): col = lane&15, row = 4*(lane>>4) + reg
  f32x4 accs[2][2] = {{acc00, acc01},{acc10, acc11}};
  #pragma unroll
  for (int mi=0; mi<2; mi++)
    #pragma unroll
    for (int ni=0; ni<2; ni++){
      int row = m0 + wr*32 + mi*16 + 4*g;
      int col = n0 + wc*32 + ni*16 + li;
      #pragma unroll
      for (int j=0; j<4; j++)
        O[(size_t)(row+j)*NC + col] = accs[mi][ni][j];
    }
}

// ---------------- per-node attention coefficients a_s, a_d ----------------
template<int HD, int H>
__global__ void k_attn(const float* __restrict__ h, const float* __restrict__ atts,
                       const float* __restrict__ attd, float* __restrict__ a_s,
                       float* __restrict__ a_d){
  int n = blockIdx.x; int t = threadIdx.x;
  float v = h[(size_t)n*HD + t];
  float ps = v*atts[t], pd = v*attd[t];
  #pragma unroll
  for (int m=32;m>=1;m>>=1){ ps += __shfl_xor(ps,m,64); pd += __shfl_xor(pd,m,64); }
  if ((t&63)==0){ int head = t>>6; a_s[n*H + head]=ps; a_d[n*H + head]=pd; }
}

// ---------------- pull-mode edge-softmax aggregation (wave-split edges) ----------------
// 4 waves per dst node; wave w handles edges st+w, st+w+4, ...; each wave reads the
// FULL h row (float4/lane for HD=256). 2-deep software pipeline on the src->h chain.
// Partials combined via LDS.
template<int HD, int H, bool ELU, bool SPLIT>
__global__ __launch_bounds__(256) void k_aggr(const float* __restrict__ h,
    const float* __restrict__ a_s, const float* __restrict__ a_d,
    const unsigned short* __restrict__ srcs, const int* __restrict__ offs,
    const float* __restrict__ bias, float* __restrict__ outf,
    short* __restrict__ outh, short* __restrict__ outl){
  constexpr int VEC = HD/64;           // 4 (HD=256) or 1 (HD=64)
  __shared__ float accL[4][HD];
  __shared__ float psumL[4][H];
  int ng = blockIdx.x;                 // b*N + n
  int b = ng >> 12, n = ng & (N_-1);
  int t = threadIdx.x;
  int w = t >> 6, l = t & 63;
  int st = offs[b*(N_+1)+n], en = offs[b*(N_+1)+n+1];
  const unsigned short* sp = &srcs[(size_t)b*ET_];
  const float* hb  = &h[(size_t)b*N_*HD];
  const float* asb = &a_s[(size_t)b*N_*H];
  int head = (H==4) ? (l >> 4) : 0;
  float adv = a_d[(size_t)ng*H + head];
  float acc[VEC];
  #pragma unroll
  for (int j=0;j<VEC;j++) acc[j]=0.f;
  float psum = 0.f;

  int i  = st + w;
  int s0 = (i   < en) ? (int)sp[i]   : 0;
  int s1 = (i+4 < en) ? (int)sp[i+4] : 0;
  float hv[VEC], asv;
  if constexpr (VEC==4){
    float4 hq = *reinterpret_cast<const float4*>(&hb[(size_t)s0*HD + l*4]);
    hv[0]=hq.x; hv[1]=hq.y; hv[2]=hq.z; hv[3]=hq.w;
  } else hv[0] = hb[(size_t)s0*HD + l];
  asv = asb[s0*H + head];

  while (i < en){
    int s2 = (i+8 < en) ? (int)sp[i+8] : 0;       // prefetch 2 ahead
    float hn[VEC], asn;
    if constexpr (VEC==4){                         // issue edge i+4 loads
      float4 hq = *reinterpret_cast<const float4*>(&hb[(size_t)s1*HD + l*4]);
      hn[0]=hq.x; hn[1]=hq.y; hn[2]=hq.z; hn[3]=hq.w;
    } else hn[0] = hb[(size_t)s1*HD + l];
    asn = asb[s1*H + head];
    float e = asv + adv;                           // compute edge i
    e = e > 0.f ? e : 0.2f*e;
    float p = __expf(e);
    #pragma unroll
    for (int j=0;j<VEC;j++) acc[j] = fmaf(p, hv[j], acc[j]);
    psum += p;
    #pragma unroll
    for (int j=0;j<VEC;j++) hv[j] = hn[j];
    asv = asn; s1 = s2; i += 4;
  }

  if constexpr (VEC==4){
    *reinterpret_cast<float4*>(&accL[w][l*4]) = make_float4(acc[0],acc[1],acc[2],acc[3]);
  } else accL[w][l] = acc[0];
  if ((l & 15) == 0 && (H==4 || l==0)) psumL[w][head] = psum;
  __syncthreads();
  if (t < HD){
    float a = accL[0][t]+accL[1][t]+accL[2][t]+accL[3][t];
    int h2 = (H==4) ? (t>>6) : 0;
    float ps = psumL[0][h2]+psumL[1][h2]+psumL[2][h2]+psumL[3][h2];
    float val = a/(ps + 1e-16f) + bias[t];
    if (ELU) val = val > 0.f ? val : expm1f(val);
    size_t idx = (size_t)ng*HD + t;
    if (SPLIT){ short hh, ll; split2(val, hh, ll); outh[idx]=hh; outl[idx]=ll; }
    else outf[idx] = val;
  }
}

// ---------------- node-mean reduction ----------------
__global__ void k_reduce(const float* __restrict__ x3, float* __restrict__ embed){
  __shared__ float red[256];
  int bid = blockIdx.x; int b = bid>>4, chunk = bid & 15;
  int t = threadIdx.x; int col = t & 63, q = t>>6;
  float s = 0.f;
  int r0 = chunk*256 + q*64;
  const float* p = &x3[((size_t)b*N_ + r0)*64 + col];
  for (int j=0;j<64;j++) s += p[(size_t)j*64];
  red[t]=s; __syncthreads();
  if (t<64){
    float v = red[t]+red[t+64]+red[t+128]+red[t+192];
    atomicAdd(&embed[b*64+t], v);
  }
}

// ---------------- classifier + log_softmax + loss + argmax ----------------
__global__ void k_final(const float* __restrict__ embed, const float* __restrict__ Wc,
                        const float* __restrict__ bc, const int* __restrict__ labels,
                        float* __restrict__ out){
  __shared__ float lg[B_][C_];
  __shared__ float lossv[B_];
  int t = threadIdx.x;
  if (t < B_*C_){
    int b = t / C_, c = t - b*C_;
    float s = 0.f;
    for (int k=0;k<64;k++) s += embed[b*64+k]*Wc[k*C_+c];
    lg[b][c] = s*(1.0f/N_) + bc[c];
  }
  __syncthreads();
  if (t < B_){
    int b = t;
    float mx = lg[b][0]; int pred = 0;
    for (int c=1;c<C_;c++) if (lg[b][c] > mx){ mx = lg[b][c]; pred = c; }
    float se = 0.f;
    for (int c=0;c<C_;c++) se += expf(lg[b][c]-mx);
    float lse = mx + logf(se);
    int lab = labels[b];
    lossv[b] = lse - lg[b][lab];
    out[b]      = (float)pred;
    out[B_+b]   = (float)lab;
  }
  __syncthreads();
  if (t==0) out[8] = 0.25f*(lossv[0]+lossv[1]+lossv[2]+lossv[3]);
}

extern "C" void kernel_launch(void* const* d_in, const int* in_sizes, int n_in,
                              void* d_out, int out_size, void* d_ws, size_t ws_size,
                              hipStream_t stream){
  const float* x0     = (const float*)d_in[0];
  const int*   labels = (const int*)d_in[1];
  const int*   ei     = (const int*)d_in[2];
  const float* W1=(const float*)d_in[3],  *as1=(const float*)d_in[4],
             *ad1=(const float*)d_in[5],  *b1 =(const float*)d_in[6];
  const float* W2=(const float*)d_in[7],  *as2=(const float*)d_in[8],
             *ad2=(const float*)d_in[9],  *b2 =(const float*)d_in[10];
  const float* W3=(const float*)d_in[11], *as3=(const float*)d_in[12],
             *ad3=(const float*)d_in[13], *b3 =(const float*)d_in[14];
  const float* Wc=(const float*)d_in[15], *bc =(const float*)d_in[16];
  float* out = (float*)d_out;

  char* ws = (char*)d_ws;
  size_t off = 0;
  auto alloc = [&](size_t bytes)->void*{ void* p = ws + off; off += (bytes + 255) & ~(size_t)255; return p; };
  float* hbuf   = (float*)alloc((size_t)B_*N_*HD_*4);    // GEMM outputs [16384,256]
  float* xcur3  = hbuf + (size_t)B_*N_*64;               // alias: layer-3 aggr out in hbuf tail
  float* a_s    = (float*)alloc((size_t)B_*N_*H_*4);
  float* a_d    = (float*)alloc((size_t)B_*N_*H_*4);
  int*   counts = (int*)alloc((size_t)B_*N_*4);
  int*   offs   = (int*)alloc((size_t)B_*(N_+1)*4);
  int*   cursor = (int*)alloc((size_t)B_*N_*4);
  unsigned short* srcs = (unsigned short*)alloc((size_t)B_*ET_*2);
  float* embed  = (float*)alloc((size_t)B_*64*4);
  short* Ah     = (short*)alloc((size_t)B_*N_*HD_*2);    // split aggr out (layers 2-3 A)
  short* Al     = (short*)alloc((size_t)B_*N_*HD_*2);
  short* Wht    = (short*)alloc((size_t)768*256*2);      // split W^T (max)
  short* Wlt    = (short*)alloc((size_t)768*256*2);

  hipMemsetAsync(counts, 0, (size_t)B_*N_*4, stream);
  hipMemsetAsync(cursor, 0, (size_t)B_*N_*4, stream);
  hipMemsetAsync(embed,  0, (size_t)B_*64*4, stream);

  int nb = (B_*ET_ + 255)/256;
  k_count  <<<nb, 256, 0, stream>>>(ei, counts);
  k_scan   <<<B_, 1024, 0, stream>>>(counts, offs);
  k_scatter<<<nb, 256, 0, stream>>>(ei, offs, cursor, srcs);

  // ---- layer 1: 768 -> 4x64, concat, elu (A = x0 fp32, split in staging) ----
  {
    k_splitT<<<(768*256+255)/256, 256, 0, stream>>>(W1, Wht, Wlt, 768, 256);
    k_mfma<768,true><<<dim3(B_*N_/64, 4), 256, 0, stream>>>(x0, nullptr, nullptr,
                                                            Wht, Wlt, hbuf, 256);
    k_attn<256,4><<<B_*N_, 256, 0, stream>>>(hbuf, as1, ad1, a_s, a_d);
    k_aggr<256,4,true,true><<<B_*N_, 256, 0, stream>>>(hbuf, a_s, a_d, srcs, offs, b1,
                                                       nullptr, Ah, Al);
  }
  // ---- layer 2: 256 -> 4x64, concat, elu ----
  {
    k_splitT<<<(256*256+255)/256, 256, 0, stream>>>(W2, Wht, Wlt, 256, 256);
    k_mfma<256,false><<<dim3(B_*N_/64, 4), 256, 0, stream>>>(nullptr, Ah, Al,
                                                             Wht, Wlt, hbuf, 256);
    k_attn<256,4><<<B_*N_, 256, 0, stream>>>(hbuf, as2, ad2, a_s, a_d);
    k_aggr<256,4,true,true><<<B_*N_, 256, 0, stream>>>(hbuf, a_s, a_d, srcs, offs, b2,
                                                       nullptr, Ah, Al);
  }
  // ---- layer 3: 256 -> 64, 1 head, mean(=identity), no elu ----
  {
    k_splitT<<<(256*64+255)/256, 256, 0, stream>>>(W3, Wht, Wlt, 256, 64);
    k_mfma<256,false><<<dim3(B_*N_/64, 1), 256, 0, stream>>>(nullptr, Ah, Al,
                                                             Wht, Wlt, hbuf, 64);
    k_attn<64,1><<<B_*N_, 64, 0, stream>>>(hbuf, as3, ad3, a_s, a_d);
    k_aggr<64,1,false,false><<<B_*N_, 256, 0, stream>>>(hbuf, a_s, a_d, srcs, offs, b3,
                                                        xcur3, nullptr, nullptr);
  }

  k_reduce<<<B_*16, 256, 0, stream>>>(xcur3, embed);
  k_final <<<1, 64, 0, stream>>>(embed, Wc, bc, labels, out);
}

// Round 6
// 376.729 us; speedup vs baseline: 1.6273x; 1.0517x over previous
//
#include <hip/hip_runtime.h>
#include <math.h>

#define B_ 4
#define N_ 4096
#define E_ 131072
#define ET_ (E_ + N_)   /* 135168 edges incl. self-loops */
#define H_ 4
#define HD_ 256
#define C_ 6

typedef short  s16x8  __attribute__((ext_vector_type(8)));
typedef __bf16 bf16x8 __attribute__((ext_vector_type(8)));
typedef float  f32x4  __attribute__((ext_vector_type(4)));

__device__ inline unsigned short f2bf(float f){
  unsigned u = __builtin_bit_cast(unsigned, f);
  return (unsigned short)((u + 0x7FFFu + ((u >> 16) & 1u)) >> 16);
}
__device__ inline float bf2f(unsigned short s){
  unsigned u = ((unsigned)s) << 16;
  return __builtin_bit_cast(float, u);
}
__device__ inline float bflo(unsigned u){ return __builtin_bit_cast(float, u << 16); }
__device__ inline float bfhi(unsigned u){ return __builtin_bit_cast(float, u & 0xFFFF0000u); }
__device__ inline void split2(float f, short& hi, short& lo){
  unsigned short h = f2bf(f);
  hi = (short)h;
  lo = (short)f2bf(f - bf2f(h));
}
__device__ inline f32x4 mfma_bf16(s16x8 a, s16x8 b, f32x4 c){
  return __builtin_amdgcn_mfma_f32_16x16x32_bf16(
      __builtin_bit_cast(bf16x8, a), __builtin_bit_cast(bf16x8, b), c, 0, 0, 0);
}

// ---------------- CSR build (counting sort by dst) ----------------
__global__ void k_count(const int* __restrict__ ei, int* __restrict__ counts){
  int idx = blockIdx.x*256 + threadIdx.x;
  if (idx >= B_*ET_) return;
  int b = idx / ET_, i = idx - b*ET_;
  int dst = (i < E_) ? ei[b*2*E_ + E_ + i] : (i - E_);
  atomicAdd(&counts[b*N_ + dst], 1);
}

__global__ void k_scan(const int* __restrict__ counts, int* __restrict__ offs){
  __shared__ int lds[1024];
  int b = blockIdx.x, t = threadIdx.x;
  int c[4]; int tot = 0;
  #pragma unroll
  for (int j=0;j<4;j++){ c[j] = counts[b*N_ + t*4 + j]; tot += c[j]; }
  lds[t] = tot; __syncthreads();
  for (int off=1; off<1024; off<<=1){
    int u = (t>=off) ? lds[t-off] : 0;
    __syncthreads();
    lds[t] += u;
    __syncthreads();
  }
  int excl = lds[t] - tot;
  int o = excl;
  #pragma unroll
  for (int j=0;j<4;j++){ offs[b*(N_+1) + t*4 + j] = o; o += c[j]; }
  if (t==1023) offs[b*(N_+1) + N_] = o;
}

__global__ void k_scatter(const int* __restrict__ ei, const int* __restrict__ offs,
                          int* __restrict__ cursor, unsigned short* __restrict__ srcs){
  int idx = blockIdx.x*256 + threadIdx.x;
  if (idx >= B_*ET_) return;
  int b = idx / ET_, i = idx - b*ET_;
  int src, dst;
  if (i < E_){ src = ei[b*2*E_ + i]; dst = ei[b*2*E_ + E_ + i]; }
  else { src = i - E_; dst = src; }
  int pos = offs[b*(N_+1) + dst] + atomicAdd(&cursor[b*N_ + dst], 1);
  srcs[b*ET_ + pos] = (unsigned short)src;
}

// split + transpose W[K,NC] -> Wt[NC,K] (hi,lo)
__global__ void k_splitT(const float* __restrict__ w, short* __restrict__ hit,
                         short* __restrict__ lot, int K, int NC){
  int idx = blockIdx.x*256 + threadIdx.x;
  if (idx >= K*NC) return;
  int nn = idx / K, kk = idx - nn*K;
  float f = w[(size_t)kk*NC + nn];
  short h, l; split2(f, h, l);
  hit[idx] = h; lot[idx] = l;
}

// ---------------- split-bf16 MFMA GEMM + fused attn epilogue ----------------
// O_bf16[M,NC] = A[M,K] @ W[K,NC]; also a_s[row] += sum_col h*atts, a_d likewise.
// A: fp32 [M,K] (AFP32, split in staging) or pre-split Ah/Al. W: Bh/Bl [NC,K].
// BM=BN=64, BK=32, 4 waves (2x2 of 32x32). head = blockIdx.y.
template<int K, bool AFP32, int H>
__global__ __launch_bounds__(256) void k_mfma(const float* __restrict__ Af,
    const short* __restrict__ Ah, const short* __restrict__ Al,
    const short* __restrict__ Bh, const short* __restrict__ Bl,
    unsigned short* __restrict__ Ob, int NC,
    const float* __restrict__ atts, const float* __restrict__ attd,
    float* __restrict__ a_s, float* __restrict__ a_d){
  __shared__ short tAh[64][32], tAl[64][32], tBh[64][32], tBl[64][32];
  int t = threadIdx.x;
  int m0 = blockIdx.x*64, n0 = blockIdx.y*64;
  int head = blockIdx.y;                 // NC=256: 64-col block == one head; NC=64: head 0
  // staging role: thread t covers row r (0..63), 16B chunk c (0..3) of the 64x32 tile
  int r = t >> 2, c = t & 3;
  int cs = (c ^ ((r >> 1) & 3)) * 8;     // XOR-swizzled chunk (in shorts)
  // compute role
  int w = t >> 6, l = t & 63;
  int wr = w >> 1, wc = w & 1, g = l >> 4, li = l & 15;
  int rA = wr*32 + li, rB = wc*32 + li;
  int cA = (g ^ ((rA >> 1) & 3)) * 8;
  int cB = (g ^ ((rB >> 1) & 3)) * 8;
  f32x4 z = {0.f,0.f,0.f,0.f};
  f32x4 acc00=z, acc01=z, acc10=z, acc11=z;

  s16x8 vah, vaL, vbh, vbl;
  auto loadSlice = [&](int k0){
    if constexpr (AFP32){
      const float* ap = &Af[(size_t)(m0+r)*K + k0 + c*8];
      float4 f0 = *reinterpret_cast<const float4*>(ap);
      float4 f1 = *reinterpret_cast<const float4*>(ap+4);
      float fv[8] = {f0.x,f0.y,f0.z,f0.w,f1.x,f1.y,f1.z,f1.w};
      #pragma unroll
      for (int j=0;j<8;j++){ short hh,ll; split2(fv[j],hh,ll); vah[j]=hh; vaL[j]=ll; }
    } else {
      vah = *reinterpret_cast<const s16x8*>(&Ah[(size_t)(m0+r)*K + k0 + c*8]);
      vaL = *reinterpret_cast<const s16x8*>(&Al[(size_t)(m0+r)*K + k0 + c*8]);
    }
    vbh = *reinterpret_cast<const s16x8*>(&Bh[(size_t)(n0+r)*K + k0 + c*8]);
    vbl = *reinterpret_cast<const s16x8*>(&Bl[(size_t)(n0+r)*K + k0 + c*8]);
  };

  loadSlice(0);
  for (int k0 = 0; k0 < K; k0 += 32){
    __syncthreads();
    *reinterpret_cast<s16x8*>(&tAh[r][cs]) = vah;
    *reinterpret_cast<s16x8*>(&tAl[r][cs]) = vaL;
    *reinterpret_cast<s16x8*>(&tBh[r][cs]) = vbh;
    *reinterpret_cast<s16x8*>(&tBl[r][cs]) = vbl;
    __syncthreads();
    if (k0 + 32 < K) loadSlice(k0 + 32);
    s16x8 a0h = *reinterpret_cast<const s16x8*>(&tAh[rA   ][cA]);
    s16x8 a1h = *reinterpret_cast<const s16x8*>(&tAh[rA+16][cA]);
    s16x8 a0l = *reinterpret_cast<const s16x8*>(&tAl[rA   ][cA]);
    s16x8 a1l = *reinterpret_cast<const s16x8*>(&tAl[rA+16][cA]);
    s16x8 b0h = *reinterpret_cast<const s16x8*>(&tBh[rB   ][cB]);
    s16x8 b1h = *reinterpret_cast<const s16x8*>(&tBh[rB+16][cB]);
    s16x8 b0l = *reinterpret_cast<const s16x8*>(&tBl[rB   ][cB]);
    s16x8 b1l = *reinterpret_cast<const s16x8*>(&tBl[rB+16][cB]);
    acc00 = mfma_bf16(a0h, b0h, acc00);
    acc00 = mfma_bf16(a0h, b0l, acc00);
    acc00 = mfma_bf16(a0l, b0h, acc00);
    acc01 = mfma_bf16(a0h, b1h, acc01);
    acc01 = mfma_bf16(a0h, b1l, acc01);
    acc01 = mfma_bf16(a0l, b1h, acc01);
    acc10 = mfma_bf16(a1h, b0h, acc10);
    acc10 = mfma_bf16(a1h, b0l, acc10);
    acc10 = mfma_bf16(a1l, b0h, acc10);
    acc11 = mfma_bf16(a1h, b1h, acc11);
    acc11 = mfma_bf16(a1h, b1l, acc11);
    acc11 = mfma_bf16(a1l, b1h, acc11);
  }
  // C/D layout: col = lane&15, row = 4*(lane>>4) + reg
  f32x4 accs[2][2] = {{acc00, acc01},{acc10, acc11}};
  float attsv[2], attdv[2];
  #pragma unroll
  for (int ni=0; ni<2; ni++){
    int colg = n0 + wc*32 + ni*16 + li;
    attsv[ni] = atts[colg];
    attdv[ni] = attd[colg];
  }
  #pragma unroll
  for (int mi=0; mi<2; mi++){
    #pragma unroll
    for (int j=0; j<4; j++){
      int row = m0 + wr*32 + mi*16 + 4*g + j;
      float sa = accs[mi][0][j]*attsv[0] + accs[mi][1][j]*attsv[1];
      float sd = accs[mi][0][j]*attdv[0] + accs[mi][1][j]*attdv[1];
      #pragma unroll
      for (int m=1; m<16; m<<=1){ sa += __shfl_xor(sa,m,64); sd += __shfl_xor(sd,m,64); }
      if (li == 0){
        atomicAdd(&a_s[(size_t)row*H + head], sa);
        atomicAdd(&a_d[(size_t)row*H + head], sd);
      }
      #pragma unroll
      for (int ni=0; ni<2; ni++){
        int col = n0 + wc*32 + ni*16 + li;
        Ob[(size_t)row*NC + col] = f2bf(accs[mi][ni][j]);
      }
    }
  }
}

// ---------------- pull-mode edge-softmax aggregation (bf16 gather) ----------------
// 4 waves per dst node; wave w handles edges st+w, st+w+4, ...; lane covers VEC cols.
// 2-deep software pipeline on the src->h chain; partials combined via LDS.
template<int HD, int H, bool ELU, bool SPLIT>
__global__ __launch_bounds__(256) void k_aggr(const unsigned short* __restrict__ h,
    const float* __restrict__ a_s, const float* __restrict__ a_d,
    const unsigned short* __restrict__ srcs, const int* __restrict__ offs,
    const float* __restrict__ bias, float* __restrict__ outf,
    short* __restrict__ outh, short* __restrict__ outl){
  constexpr int VEC = HD/64;           // 4 (HD=256) or 1 (HD=64)
  __shared__ float accL[4][HD];
  __shared__ float psumL[4][H];
  int ng = blockIdx.x;                 // b*N + n
  int b = ng >> 12, n = ng & (N_-1);
  int t = threadIdx.x;
  int w = t >> 6, l = t & 63;
  int st = offs[b*(N_+1)+n], en = offs[b*(N_+1)+n+1];
  const unsigned short* sp = &srcs[(size_t)b*ET_];
  const unsigned short* hb = &h[(size_t)b*N_*HD];
  const float* asb = &a_s[(size_t)b*N_*H];
  int head = (H==4) ? (l >> 4) : 0;
  float adv = a_d[(size_t)ng*H + head];
  float acc[VEC];
  #pragma unroll
  for (int j=0;j<VEC;j++) acc[j]=0.f;
  float psum = 0.f;

  int i  = st + w;
  int s0 = (i   < en) ? (int)sp[i]   : 0;
  int s1 = (i+4 < en) ? (int)sp[i+4] : 0;
  float hv[VEC], asv;
  if constexpr (VEC==4){
    uint2 q = *reinterpret_cast<const uint2*>(&hb[(size_t)s0*HD + l*4]);
    hv[0]=bflo(q.x); hv[1]=bfhi(q.x); hv[2]=bflo(q.y); hv[3]=bfhi(q.y);
  } else hv[0] = bflo((unsigned)hb[(size_t)s0*HD + l]);
  asv = asb[s0*H + head];

  while (i < en){
    int s2 = (i+8 < en) ? (int)sp[i+8] : 0;       // prefetch 2 ahead
    float hn[VEC], asn;
    if constexpr (VEC==4){                         // issue edge i+4 loads
      uint2 q = *reinterpret_cast<const uint2*>(&hb[(size_t)s1*HD + l*4]);
      hn[0]=bflo(q.x); hn[1]=bfhi(q.x); hn[2]=bflo(q.y); hn[3]=bfhi(q.y);
    } else hn[0] = bflo((unsigned)hb[(size_t)s1*HD + l]);
    asn = asb[s1*H + head];
    float e = asv + adv;                           // compute edge i
    e = e > 0.f ? e : 0.2f*e;
    float p = __expf(e);
    #pragma unroll
    for (int j=0;j<VEC;j++) acc[j] = fmaf(p, hv[j], acc[j]);
    psum += p;
    #pragma unroll
    for (int j=0;j<VEC;j++) hv[j] = hn[j];
    asv = asn; s1 = s2; i += 4;
  }

  if constexpr (VEC==4){
    *reinterpret_cast<float4*>(&accL[w][l*4]) = make_float4(acc[0],acc[1],acc[2],acc[3]);
  } else accL[w][l] = acc[0];
  if ((l & 15) == 0 && (H==4 || l==0)) psumL[w][head] = psum;
  __syncthreads();
  if (t < HD){
    float a = accL[0][t]+accL[1][t]+accL[2][t]+accL[3][t];
    int h2 = (H==4) ? (t>>6) : 0;
    float ps = psumL[0][h2]+psumL[1][h2]+psumL[2][h2]+psumL[3][h2];
    float val = a/(ps + 1e-16f) + bias[t];
    if (ELU) val = val > 0.f ? val : expm1f(val);
    size_t idx = (size_t)ng*HD + t;
    if (SPLIT){ short hh, ll; split2(val, hh, ll); outh[idx]=hh; outl[idx]=ll; }
    else outf[idx] = val;
  }
}

// ---------------- node-mean reduction ----------------
__global__ void k_reduce(const float* __restrict__ x3, float* __restrict__ embed){
  __shared__ float red[256];
  int bid = blockIdx.x; int b = bid>>4, chunk = bid & 15;
  int t = threadIdx.x; int col = t & 63, q = t>>6;
  float s = 0.f;
  int r0 = chunk*256 + q*64;
  const float* p = &x3[((size_t)b*N_ + r0)*64 + col];
  for (int j=0;j<64;j++) s += p[(size_t)j*64];
  red[t]=s; __syncthreads();
  if (t<64){
    float v = red[t]+red[t+64]+red[t+128]+red[t+192];
    atomicAdd(&embed[b*64+t], v);
  }
}

// ---------------- classifier + log_softmax + loss + argmax ----------------
__global__ void k_final(const float* __restrict__ embed, const float* __restrict__ Wc,
                        const float* __restrict__ bc, const int* __restrict__ labels,
                        float* __restrict__ out){
  __shared__ float lg[B_][C_];
  __shared__ float lossv[B_];
  int t = threadIdx.x;
  if (t < B_*C_){
    int b = t / C_, c = t - b*C_;
    float s = 0.f;
    for (int k=0;k<64;k++) s += embed[b*64+k]*Wc[k*C_+c];
    lg[b][c] = s*(1.0f/N_) + bc[c];
  }
  __syncthreads();
  if (t < B_){
    int b = t;
    float mx = lg[b][0]; int pred = 0;
    for (int c=1;c<C_;c++) if (lg[b][c] > mx){ mx = lg[b][c]; pred = c; }
    float se = 0.f;
    for (int c=0;c<C_;c++) se += expf(lg[b][c]-mx);
    float lse = mx + logf(se);
    int lab = labels[b];
    lossv[b] = lse - lg[b][lab];
    out[b]      = (float)pred;
    out[B_+b]   = (float)lab;
  }
  __syncthreads();
  if (t==0) out[8] = 0.25f*(lossv[0]+lossv[1]+lossv[2]+lossv[3]);
}

extern "C" void kernel_launch(void* const* d_in, const int* in_sizes, int n_in,
                              void* d_out, int out_size, void* d_ws, size_t ws_size,
                              hipStream_t stream){
  const float* x0     = (const float*)d_in[0];
  const int*   labels = (const int*)d_in[1];
  const int*   ei     = (const int*)d_in[2];
  const float* W1=(const float*)d_in[3],  *as1=(const float*)d_in[4],
             *ad1=(const float*)d_in[5],  *b1 =(const float*)d_in[6];
  const float* W2=(const float*)d_in[7],  *as2=(const float*)d_in[8],
             *ad2=(const float*)d_in[9],  *b2 =(const float*)d_in[10];
  const float* W3=(const float*)d_in[11], *as3=(const float*)d_in[12],
             *ad3=(const float*)d_in[13], *b3 =(const float*)d_in[14];
  const float* Wc=(const float*)d_in[15], *bc =(const float*)d_in[16];
  float* out = (float*)d_out;

  char* ws = (char*)d_ws;
  size_t off = 0;
  auto alloc = [&](size_t bytes)->void*{ void* p = ws + off; off += (bytes + 255) & ~(size_t)255; return p; };
  unsigned short* hbuf = (unsigned short*)alloc((size_t)B_*N_*HD_*2); // GEMM out, bf16
  float* xcur3  = (float*)alloc((size_t)B_*N_*64*4);     // layer-3 aggr out (fp32)
  int*   counts = (int*)alloc((size_t)B_*N_*4);
  int*   cursor = (int*)alloc((size_t)B_*N_*4);
  int*   offs   = (int*)alloc((size_t)B_*(N_+1)*4);
  unsigned short* srcs = (unsigned short*)alloc((size_t)B_*ET_*2);
  float* embed  = (float*)alloc((size_t)B_*64*4);
  float* a_s1   = (float*)alloc((size_t)B_*N_*H_*4);     // zeroed block start
  float* a_d1   = (float*)alloc((size_t)B_*N_*H_*4);
  float* a_s2   = (float*)alloc((size_t)B_*N_*H_*4);
  float* a_d2   = (float*)alloc((size_t)B_*N_*H_*4);
  float* a_s3   = (float*)alloc((size_t)B_*N_*4);
  float* a_d3   = (float*)alloc((size_t)B_*N_*4);
  size_t zend   = off;                                   // zeroed block end
  short* Ah     = (short*)alloc((size_t)B_*N_*HD_*2);    // split aggr out (layers 2-3 A)
  short* Al     = (short*)alloc((size_t)B_*N_*HD_*2);
  short* Wht    = (short*)alloc((size_t)768*256*2);      // split W^T (max)
  short* Wlt    = (short*)alloc((size_t)768*256*2);

  hipMemsetAsync(counts, 0, (size_t)B_*N_*4*2, stream);            // counts+cursor
  hipMemsetAsync(embed,  0, zend - ((char*)embed - ws), stream);   // embed + a_s/a_d x3

  int nb = (B_*ET_ + 255)/256;
  k_count  <<<nb, 256, 0, stream>>>(ei, counts);
  k_scan   <<<B_, 1024, 0, stream>>>(counts, offs);
  k_scatter<<<nb, 256, 0, stream>>>(ei, offs, cursor, srcs);

  // ---- layer 1: 768 -> 4x64, concat, elu (A = x0 fp32, split in staging) ----
  {
    k_splitT<<<(768*256+255)/256, 256, 0, stream>>>(W1, Wht, Wlt, 768, 256);
    k_mfma<768,true,4><<<dim3(B_*N_/64, 4), 256, 0, stream>>>(x0, nullptr, nullptr,
        Wht, Wlt, hbuf, 256, as1, ad1, a_s1, a_d1);
    k_aggr<256,4,true,true><<<B_*N_, 256, 0, stream>>>(hbuf, a_s1, a_d1, srcs, offs, b1,
                                                       nullptr, Ah, Al);
  }
  // ---- layer 2: 256 -> 4x64, concat, elu ----
  {
    k_splitT<<<(256*256+255)/256, 256, 0, stream>>>(W2, Wht, Wlt, 256, 256);
    k_mfma<256,false,4><<<dim3(B_*N_/64, 4), 256, 0, stream>>>(nullptr, Ah, Al,
        Wht, Wlt, hbuf, 256, as2, ad2, a_s2, a_d2);
    k_aggr<256,4,true,true><<<B_*N_, 256, 0, stream>>>(hbuf, a_s2, a_d2, srcs, offs, b2,
                                                       nullptr, Ah, Al);
  }
  // ---- layer 3: 256 -> 64, 1 head, mean(=identity), no elu ----
  {
    k_splitT<<<(256*64+255)/256, 256, 0, stream>>>(W3, Wht, Wlt, 256, 64);
    k_mfma<256,false,1><<<dim3(B_*N_/64, 1), 256, 0, stream>>>(nullptr, Ah, Al,
        Wht, Wlt, hbuf, 64, as3, ad3, a_s3, a_d3);
    k_aggr<64,1,false,false><<<B_*N_, 256, 0, stream>>>(hbuf, a_s3, a_d3, srcs, offs, b3,
                                                        xcur3, nullptr, nullptr);
  }

  k_reduce<<<B_*16, 256, 0, stream>>>(xcur3, embed);
  k_final <<<1, 64, 0, stream>>>(embed, Wc, bc, labels, out);
}

// Round 7
// 340.997 us; speedup vs baseline: 1.7979x; 1.1048x over previous
//
#include <hip/hip_runtime.h>
#include <math.h>

#define B_ 4
#define N_ 4096
#define E_ 131072
#define ET_ (E_ + N_)   /* 135168 edges incl. self-loops */
#define H_ 4
#define HD_ 256
#define C_ 6

typedef short  s16x8  __attribute__((ext_vector_type(8)));
typedef __bf16 bf16x8 __attribute__((ext_vector_type(8)));
typedef float  f32x4  __attribute__((ext_vector_type(4)));

__device__ inline unsigned short f2bf(float f){
  unsigned u = __builtin_bit_cast(unsigned, f);
  return (unsigned short)((u + 0x7FFFu + ((u >> 16) & 1u)) >> 16);
}
__device__ inline float bf2f(unsigned short s){
  unsigned u = ((unsigned)s) << 16;
  return __builtin_bit_cast(float, u);
}
__device__ inline float bflo(unsigned u){ return __builtin_bit_cast(float, u << 16); }
__device__ inline float bfhi(unsigned u){ return __builtin_bit_cast(float, u & 0xFFFF0000u); }
__device__ inline void split2(float f, short& hi, short& lo){
  unsigned short h = f2bf(f);
  hi = (short)h;
  lo = (short)f2bf(f - bf2f(h));
}
__device__ inline f32x4 mfma_bf16(s16x8 a, s16x8 b, f32x4 c){
  return __builtin_amdgcn_mfma_f32_16x16x32_bf16(
      __builtin_bit_cast(bf16x8, a), __builtin_bit_cast(bf16x8, b), c, 0, 0, 0);
}

// ---------------- CSR build (counting sort by dst) ----------------
__global__ void k_count(const int* __restrict__ ei, int* __restrict__ counts){
  int idx = blockIdx.x*256 + threadIdx.x;
  if (idx >= B_*ET_) return;
  int b = idx / ET_, i = idx - b*ET_;
  int dst = (i < E_) ? ei[b*2*E_ + E_ + i] : (i - E_);
  atomicAdd(&counts[b*N_ + dst], 1);
}

__global__ void k_scan(const int* __restrict__ counts, int* __restrict__ offs){
  __shared__ int lds[1024];
  int b = blockIdx.x, t = threadIdx.x;
  int c[4]; int tot = 0;
  #pragma unroll
  for (int j=0;j<4;j++){ c[j] = counts[b*N_ + t*4 + j]; tot += c[j]; }
  lds[t] = tot; __syncthreads();
  for (int off=1; off<1024; off<<=1){
    int u = (t>=off) ? lds[t-off] : 0;
    __syncthreads();
    lds[t] += u;
    __syncthreads();
  }
  int excl = lds[t] - tot;
  int o = excl;
  #pragma unroll
  for (int j=0;j<4;j++){ offs[b*(N_+1) + t*4 + j] = o; o += c[j]; }
  if (t==1023) offs[b*(N_+1) + N_] = o;
}

__global__ void k_scatter(const int* __restrict__ ei, const int* __restrict__ offs,
                          int* __restrict__ cursor, unsigned short* __restrict__ srcs){
  int idx = blockIdx.x*256 + threadIdx.x;
  if (idx >= B_*ET_) return;
  int b = idx / ET_, i = idx - b*ET_;
  int src, dst;
  if (i < E_){ src = ei[b*2*E_ + i]; dst = ei[b*2*E_ + E_ + i]; }
  else { src = i - E_; dst = src; }
  int pos = offs[b*(N_+1) + dst] + atomicAdd(&cursor[b*N_ + dst], 1);
  srcs[b*ET_ + pos] = (unsigned short)src;
}

// split + transpose W[K,NC] -> Wt[NC,K] (hi,lo)
__global__ void k_splitT(const float* __restrict__ w, short* __restrict__ hit,
                         short* __restrict__ lot, int K, int NC){
  int idx = blockIdx.x*256 + threadIdx.x;
  if (idx >= K*NC) return;
  int nn = idx / K, kk = idx - nn*K;
  float f = w[(size_t)kk*NC + nn];
  short h, l; split2(f, h, l);
  hit[idx] = h; lot[idx] = l;
}

// ---------------- split-bf16 MFMA GEMM + fused attn epilogue ----------------
// O_bf16[M,NC] = A[M,K] @ W[K,NC]; also a_s[row] += sum_col h*atts, a_d likewise.
// A: fp32 [M,K] (AFP32, split in staging) or pre-split Ah/Al. W: Bh/Bl [NC,K].
// BM=BN=64, BK=32, 4 waves (2x2 of 32x32). head = blockIdx.y.
template<int K, bool AFP32, int H>
__global__ __launch_bounds__(256) void k_mfma(const float* __restrict__ Af,
    const short* __restrict__ Ah, const short* __restrict__ Al,
    const short* __restrict__ Bh, const short* __restrict__ Bl,
    unsigned short* __restrict__ Ob, int NC,
    const float* __restrict__ atts, const float* __restrict__ attd,
    float* __restrict__ a_s, float* __restrict__ a_d){
  __shared__ short tAh[64][32], tAl[64][32], tBh[64][32], tBl[64][32];
  int t = threadIdx.x;
  int m0 = blockIdx.x*64, n0 = blockIdx.y*64;
  int head = blockIdx.y;                 // NC=256: 64-col block == one head; NC=64: head 0
  // staging role: thread t covers row r (0..63), 16B chunk c (0..3) of the 64x32 tile
  int r = t >> 2, c = t & 3;
  int cs = (c ^ ((r >> 1) & 3)) * 8;     // XOR-swizzled chunk (in shorts)
  // compute role
  int w = t >> 6, l = t & 63;
  int wr = w >> 1, wc = w & 1, g = l >> 4, li = l & 15;
  int rA = wr*32 + li, rB = wc*32 + li;
  int cA = (g ^ ((rA >> 1) & 3)) * 8;
  int cB = (g ^ ((rB >> 1) & 3)) * 8;
  f32x4 z = {0.f,0.f,0.f,0.f};
  f32x4 acc00=z, acc01=z, acc10=z, acc11=z;

  s16x8 vah, vaL, vbh, vbl;
  auto loadSlice = [&](int k0){
    if constexpr (AFP32){
      const float* ap = &Af[(size_t)(m0+r)*K + k0 + c*8];
      float4 f0 = *reinterpret_cast<const float4*>(ap);
      float4 f1 = *reinterpret_cast<const float4*>(ap+4);
      float fv[8] = {f0.x,f0.y,f0.z,f0.w,f1.x,f1.y,f1.z,f1.w};
      #pragma unroll
      for (int j=0;j<8;j++){ short hh,ll; split2(fv[j],hh,ll); vah[j]=hh; vaL[j]=ll; }
    } else {
      vah = *reinterpret_cast<const s16x8*>(&Ah[(size_t)(m0+r)*K + k0 + c*8]);
      vaL = *reinterpret_cast<const s16x8*>(&Al[(size_t)(m0+r)*K + k0 + c*8]);
    }
    vbh = *reinterpret_cast<const s16x8*>(&Bh[(size_t)(n0+r)*K + k0 + c*8]);
    vbl = *reinterpret_cast<const s16x8*>(&Bl[(size_t)(n0+r)*K + k0 + c*8]);
  };

  loadSlice(0);
  for (int k0 = 0; k0 < K; k0 += 32){
    __syncthreads();
    *reinterpret_cast<s16x8*>(&tAh[r][cs]) = vah;
    *reinterpret_cast<s16x8*>(&tAl[r][cs]) = vaL;
    *reinterpret_cast<s16x8*>(&tBh[r][cs]) = vbh;
    *reinterpret_cast<s16x8*>(&tBl[r][cs]) = vbl;
    __syncthreads();
    if (k0 + 32 < K) loadSlice(k0 + 32);
    s16x8 a0h = *reinterpret_cast<const s16x8*>(&tAh[rA   ][cA]);
    s16x8 a1h = *reinterpret_cast<const s16x8*>(&tAh[rA+16][cA]);
    s16x8 a0l = *reinterpret_cast<const s16x8*>(&tAl[rA   ][cA]);
    s16x8 a1l = *reinterpret_cast<const s16x8*>(&tAl[rA+16][cA]);
    s16x8 b0h = *reinterpret_cast<const s16x8*>(&tBh[rB   ][cB]);
    s16x8 b1h = *reinterpret_cast<const s16x8*>(&tBh[rB+16][cB]);
    s16x8 b0l = *reinterpret_cast<const s16x8*>(&tBl[rB   ][cB]);
    s16x8 b1l = *reinterpret_cast<const s16x8*>(&tBl[rB+16][cB]);
    acc00 = mfma_bf16(a0h, b0h, acc00);
    acc00 = mfma_bf16(a0h, b0l, acc00);
    acc00 = mfma_bf16(a0l, b0h, acc00);
    acc01 = mfma_bf16(a0h, b1h, acc01);
    acc01 = mfma_bf16(a0h, b1l, acc01);
    acc01 = mfma_bf16(a0l, b1h, acc01);
    acc10 = mfma_bf16(a1h, b0h, acc10);
    acc10 = mfma_bf16(a1h, b0l, acc10);
    acc10 = mfma_bf16(a1l, b0h, acc10);
    acc11 = mfma_bf16(a1h, b1h, acc11);
    acc11 = mfma_bf16(a1h, b1l, acc11);
    acc11 = mfma_bf16(a1l, b1h, acc11);
  }
  // C/D layout: col = lane&15, row = 4*(lane>>4) + reg
  f32x4 accs[2][2] = {{acc00, acc01},{acc10, acc11}};
  float attsv[2], attdv[2];
  #pragma unroll
  for (int ni=0; ni<2; ni++){
    int colg = n0 + wc*32 + ni*16 + li;
    attsv[ni] = atts[colg];
    attdv[ni] = attd[colg];
  }
  #pragma unroll
  for (int mi=0; mi<2; mi++){
    #pragma unroll
    for (int j=0; j<4; j++){
      int row = m0 + wr*32 + mi*16 + 4*g + j;
      float sa = accs[mi][0][j]*attsv[0] + accs[mi][1][j]*attsv[1];
      float sd = accs[mi][0][j]*attdv[0] + accs[mi][1][j]*attdv[1];
      #pragma unroll
      for (int m=1; m<16; m<<=1){ sa += __shfl_xor(sa,m,64); sd += __shfl_xor(sd,m,64); }
      if (li == 0){
        atomicAdd(&a_s[(size_t)row*H + head], sa);
        atomicAdd(&a_d[(size_t)row*H + head], sd);
      }
      #pragma unroll
      for (int ni=0; ni<2; ni++){
        int col = n0 + wc*32 + ni*16 + li;
        Ob[(size_t)row*NC + col] = f2bf(accs[mi][ni][j]);
      }
    }
  }
}

// ---------------- pull-mode edge-softmax aggregation (multi-edge waves) ----------------
// HD=256: 2 edges/wave (32 lanes x uint4 = 8 bf16 each); HD=64: 4 edges/wave
// (16 lanes x uint2). 8/16 edge-slots per block, 2-deep pipeline per slot,
// partials combined via LDS.
template<int HD, int H, bool ELU, bool SPLIT>
__global__ __launch_bounds__(256) void k_aggr(const unsigned short* __restrict__ h,
    const float* __restrict__ a_s, const float* __restrict__ a_d,
    const unsigned short* __restrict__ srcs, const int* __restrict__ offs,
    const float* __restrict__ bias, float* __restrict__ outf,
    short* __restrict__ outh, short* __restrict__ outl){
  constexpr int EPW = (HD==256) ? 2 : 4;   // edges per wave
  constexpr int LPE = 64/EPW;              // lanes per edge: 32 or 16
  constexpr int CPL = HD/LPE;              // cols per lane: 8 or 4
  constexpr int NP  = 4*EPW;               // edge slots per block: 8 or 16
  __shared__ float accL[NP][HD];
  __shared__ float psumL[NP][H];
  int ng = blockIdx.x;                     // b*N + n
  int b = ng >> 12, n = ng & (N_-1);
  int t = threadIdx.x;
  int w = t >> 6, l = t & 63;
  int sub = l / LPE, hl = l % LPE;
  int slot = w*EPW + sub;
  int st = offs[b*(N_+1)+n], en = offs[b*(N_+1)+n+1];
  const unsigned short* sp = &srcs[(size_t)b*ET_];
  const unsigned short* hb = &h[(size_t)b*N_*HD];
  const float* asb = &a_s[(size_t)b*N_*H];
  int head = (H==4) ? ((hl*CPL) >> 6) : 0;
  float adv = a_d[(size_t)ng*H + head];
  float acc[CPL];
  #pragma unroll
  for (int j=0;j<CPL;j++) acc[j]=0.f;
  float psum = 0.f;

  auto ldh = [&](int s, float* dst){
    const unsigned short* p = &hb[(size_t)s*HD + hl*CPL];
    if constexpr (CPL==8){
      uint4 q = *reinterpret_cast<const uint4*>(p);
      dst[0]=bflo(q.x); dst[1]=bfhi(q.x); dst[2]=bflo(q.y); dst[3]=bfhi(q.y);
      dst[4]=bflo(q.z); dst[5]=bfhi(q.z); dst[6]=bflo(q.w); dst[7]=bfhi(q.w);
    } else {
      uint2 q = *reinterpret_cast<const uint2*>(p);
      dst[0]=bflo(q.x); dst[1]=bfhi(q.x); dst[2]=bflo(q.y); dst[3]=bfhi(q.y);
    }
  };

  int i  = st + slot;
  int s0 = (i      < en) ? (int)sp[i]      : 0;
  int s1 = (i+NP   < en) ? (int)sp[i+NP]   : 0;
  float hv[CPL], hn[CPL], asv, asn;
  ldh(s0, hv); asv = asb[s0*H + head];

  while (i < en){
    int s2 = (i+2*NP < en) ? (int)sp[i+2*NP] : 0;   // prefetch 2 ahead
    ldh(s1, hn); asn = asb[s1*H + head];            // issue next slot loads
    float e = asv + adv;                            // compute current edge
    e = fmaxf(e, 0.2f*e);                           // leaky_relu
    float p = __expf(e);
    #pragma unroll
    for (int j=0;j<CPL;j++) acc[j] = fmaf(p, hv[j], acc[j]);
    psum += p;
    #pragma unroll
    for (int j=0;j<CPL;j++) hv[j] = hn[j];
    asv = asn; s1 = s2; i += NP;
  }

  #pragma unroll
  for (int j=0;j<CPL;j+=4)
    *reinterpret_cast<float4*>(&accL[slot][hl*CPL+j]) =
        make_float4(acc[j],acc[j+1],acc[j+2],acc[j+3]);
  if constexpr (H==4){ if ((hl & 7)==0) psumL[slot][hl>>3] = psum; }
  else               { if (hl == 0)     psumL[slot][0]     = psum; }
  __syncthreads();
  if (t < HD){
    float a = 0.f;
    #pragma unroll
    for (int k=0;k<NP;k++) a += accL[k][t];
    int h2 = (H==4) ? (t>>6) : 0;
    float ps = 0.f;
    #pragma unroll
    for (int k=0;k<NP;k++) ps += psumL[k][h2];
    float val = a/(ps + 1e-16f) + bias[t];
    if (ELU) val = val > 0.f ? val : expm1f(val);
    size_t idx = (size_t)ng*HD + t;
    if (SPLIT){ short hh, ll; split2(val, hh, ll); outh[idx]=hh; outl[idx]=ll; }
    else outf[idx] = val;
  }
}

// ---------------- node-mean reduction ----------------
__global__ void k_reduce(const float* __restrict__ x3, float* __restrict__ embed){
  __shared__ float red[256];
  int bid = blockIdx.x; int b = bid>>4, chunk = bid & 15;
  int t = threadIdx.x; int col = t & 63, q = t>>6;
  float s = 0.f;
  int r0 = chunk*256 + q*64;
  const float* p = &x3[((size_t)b*N_ + r0)*64 + col];
  for (int j=0;j<64;j++) s += p[(size_t)j*64];
  red[t]=s; __syncthreads();
  if (t<64){
    float v = red[t]+red[t+64]+red[t+128]+red[t+192];
    atomicAdd(&embed[b*64+t], v);
  }
}

// ---------------- classifier + log_softmax + loss + argmax ----------------
__global__ void k_final(const float* __restrict__ embed, const float* __restrict__ Wc,
                        const float* __restrict__ bc, const int* __restrict__ labels,
                        float* __restrict__ out){
  __shared__ float lg[B_][C_];
  __shared__ float lossv[B_];
  int t = threadIdx.x;
  if (t < B_*C_){
    int b = t / C_, c = t - b*C_;
    float s = 0.f;
    for (int k=0;k<64;k++) s += embed[b*64+k]*Wc[k*C_+c];
    lg[b][c] = s*(1.0f/N_) + bc[c];
  }
  __syncthreads();
  if (t < B_){
    int b = t;
    float mx = lg[b][0]; int pred = 0;
    for (int c=1;c<C_;c++) if (lg[b][c] > mx){ mx = lg[b][c]; pred = c; }
    float se = 0.f;
    for (int c=0;c<C_;c++) se += expf(lg[b][c]-mx);
    float lse = mx + logf(se);
    int lab = labels[b];
    lossv[b] = lse - lg[b][lab];
    out[b]      = (float)pred;
    out[B_+b]   = (float)lab;
  }
  __syncthreads();
  if (t==0) out[8] = 0.25f*(lossv[0]+lossv[1]+lossv[2]+lossv[3]);
}

extern "C" void kernel_launch(void* const* d_in, const int* in_sizes, int n_in,
                              void* d_out, int out_size, void* d_ws, size_t ws_size,
                              hipStream_t stream){
  const float* x0     = (const float*)d_in[0];
  const int*   labels = (const int*)d_in[1];
  const int*   ei     = (const int*)d_in[2];
  const float* W1=(const float*)d_in[3],  *as1=(const float*)d_in[4],
             *ad1=(const float*)d_in[5],  *b1 =(const float*)d_in[6];
  const float* W2=(const float*)d_in[7],  *as2=(const float*)d_in[8],
             *ad2=(const float*)d_in[9],  *b2 =(const float*)d_in[10];
  const float* W3=(const float*)d_in[11], *as3=(const float*)d_in[12],
             *ad3=(const float*)d_in[13], *b3 =(const float*)d_in[14];
  const float* Wc=(const float*)d_in[15], *bc =(const float*)d_in[16];
  float* out = (float*)d_out;

  char* ws = (char*)d_ws;
  size_t off = 0;
  auto alloc = [&](size_t bytes)->void*{ void* p = ws + off; off += (bytes + 255) & ~(size_t)255; return p; };
  unsigned short* hbuf = (unsigned short*)alloc((size_t)B_*N_*HD_*2); // GEMM out, bf16
  float* xcur3  = (float*)alloc((size_t)B_*N_*64*4);     // layer-3 aggr out (fp32)
  int*   counts = (int*)alloc((size_t)B_*N_*4);
  int*   cursor = (int*)alloc((size_t)B_*N_*4);
  int*   offs   = (int*)alloc((size_t)B_*(N_+1)*4);
  unsigned short* srcs = (unsigned short*)alloc((size_t)B_*ET_*2);
  float* embed  = (float*)alloc((size_t)B_*64*4);
  float* a_s1   = (float*)alloc((size_t)B_*N_*H_*4);     // zeroed block start
  float* a_d1   = (float*)alloc((size_t)B_*N_*H_*4);
  float* a_s2   = (float*)alloc((size_t)B_*N_*H_*4);
  float* a_d2   = (float*)alloc((size_t)B_*N_*H_*4);
  float* a_s3   = (float*)alloc((size_t)B_*N_*4);
  float* a_d3   = (float*)alloc((size_t)B_*N_*4);
  size_t zend   = off;                                   // zeroed block end
  short* Ah     = (short*)alloc((size_t)B_*N_*HD_*2);    // split aggr out (layers 2-3 A)
  short* Al     = (short*)alloc((size_t)B_*N_*HD_*2);
  short* Wht    = (short*)alloc((size_t)768*256*2);      // split W^T (max)
  short* Wlt    = (short*)alloc((size_t)768*256*2);

  hipMemsetAsync(counts, 0, (size_t)B_*N_*4*2, stream);            // counts+cursor
  hipMemsetAsync(embed,  0, zend - ((char*)embed - ws), stream);   // embed + a_s/a_d x3

  int nb = (B_*ET_ + 255)/256;
  k_count  <<<nb, 256, 0, stream>>>(ei, counts);
  k_scan   <<<B_, 1024, 0, stream>>>(counts, offs);
  k_scatter<<<nb, 256, 0, stream>>>(ei, offs, cursor, srcs);

  // ---- layer 1: 768 -> 4x64, concat, elu (A = x0 fp32, split in staging) ----
  {
    k_splitT<<<(768*256+255)/256, 256, 0, stream>>>(W1, Wht, Wlt, 768, 256);
    k_mfma<768,true,4><<<dim3(B_*N_/64, 4), 256, 0, stream>>>(x0, nullptr, nullptr,
        Wht, Wlt, hbuf, 256, as1, ad1, a_s1, a_d1);
    k_aggr<256,4,true,true><<<B_*N_, 256, 0, stream>>>(hbuf, a_s1, a_d1, srcs, offs, b1,
                                                       nullptr, Ah, Al);
  }
  // ---- layer 2: 256 -> 4x64, concat, elu ----
  {
    k_splitT<<<(256*256+255)/256, 256, 0, stream>>>(W2, Wht, Wlt, 256, 256);
    k_mfma<256,false,4><<<dim3(B_*N_/64, 4), 256, 0, stream>>>(nullptr, Ah, Al,
        Wht, Wlt, hbuf, 256, as2, ad2, a_s2, a_d2);
    k_aggr<256,4,true,true><<<B_*N_, 256, 0, stream>>>(hbuf, a_s2, a_d2, srcs, offs, b2,
                                                       nullptr, Ah, Al);
  }
  // ---- layer 3: 256 -> 64, 1 head, mean(=identity), no elu ----
  {
    k_splitT<<<(256*64+255)/256, 256, 0, stream>>>(W3, Wht, Wlt, 256, 64);
    k_mfma<256,false,1><<<dim3(B_*N_/64, 1), 256, 0, stream>>>(nullptr, Ah, Al,
        Wht, Wlt, hbuf, 64, as3, ad3, a_s3, a_d3);
    k_aggr<64,1,false,false><<<B_*N_, 256, 0, stream>>>(hbuf, a_s3, a_d3, srcs, offs, b3,
                                                        xcur3, nullptr, nullptr);
  }

  k_reduce<<<B_*16, 256, 0, stream>>>(xcur3, embed);
  k_final <<<1, 64, 0, stream>>>(embed, Wc, bc, labels, out);
}

// Round 8
// 333.594 us; speedup vs baseline: 1.8378x; 1.0222x over previous
//
#include <hip/hip_runtime.h>
#include <math.h>

#define B_ 4
#define N_ 4096
#define E_ 131072
#define ET_ (E_ + N_)   /* 135168 edges incl. self-loops */
#define H_ 4
#define HD_ 256
#define C_ 6

typedef short  s16x8  __attribute__((ext_vector_type(8)));
typedef __bf16 bf16x8 __attribute__((ext_vector_type(8)));
typedef float  f32x4  __attribute__((ext_vector_type(4)));

__device__ inline unsigned short f2bf(float f){
  unsigned u = __builtin_bit_cast(unsigned, f);
  return (unsigned short)((u + 0x7FFFu + ((u >> 16) & 1u)) >> 16);
}
__device__ inline float bf2f(unsigned short s){
  unsigned u = ((unsigned)s) << 16;
  return __builtin_bit_cast(float, u);
}
__device__ inline float bflo(unsigned u){ return __builtin_bit_cast(float, u << 16); }
__device__ inline float bfhi(unsigned u){ return __builtin_bit_cast(float, u & 0xFFFF0000u); }
__device__ inline void split2(float f, short& hi, short& lo){
  unsigned short h = f2bf(f);
  hi = (short)h;
  lo = (short)f2bf(f - bf2f(h));
}
__device__ inline f32x4 mfma_bf16(s16x8 a, s16x8 b, f32x4 c){
  return __builtin_amdgcn_mfma_f32_16x16x32_bf16(
      __builtin_bit_cast(bf16x8, a), __builtin_bit_cast(bf16x8, b), c, 0, 0, 0);
}

// ---------------- CSR build (counting sort by dst) ----------------
__global__ void k_count(const int* __restrict__ ei, int* __restrict__ counts){
  int idx = blockIdx.x*256 + threadIdx.x;
  if (idx >= B_*ET_) return;
  int b = idx / ET_, i = idx - b*ET_;
  int dst = (i < E_) ? ei[b*2*E_ + E_ + i] : (i - E_);
  atomicAdd(&counts[b*N_ + dst], 1);
}

__global__ void k_scan(const int* __restrict__ counts, int* __restrict__ offs){
  __shared__ int lds[1024];
  int b = blockIdx.x, t = threadIdx.x;
  int c[4]; int tot = 0;
  #pragma unroll
  for (int j=0;j<4;j++){ c[j] = counts[b*N_ + t*4 + j]; tot += c[j]; }
  lds[t] = tot; __syncthreads();
  for (int off=1; off<1024; off<<=1){
    int u = (t>=off) ? lds[t-off] : 0;
    __syncthreads();
    lds[t] += u;
    __syncthreads();
  }
  int excl = lds[t] - tot;
  int o = excl;
  #pragma unroll
  for (int j=0;j<4;j++){ offs[b*(N_+1) + t*4 + j] = o; o += c[j]; }
  if (t==1023) offs[b*(N_+1) + N_] = o;
}

__global__ void k_scatter(const int* __restrict__ ei, const int* __restrict__ offs,
                          int* __restrict__ cursor, unsigned short* __restrict__ srcs){
  int idx = blockIdx.x*256 + threadIdx.x;
  if (idx >= B_*ET_) return;
  int b = idx / ET_, i = idx - b*ET_;
  int src, dst;
  if (i < E_){ src = ei[b*2*E_ + i]; dst = ei[b*2*E_ + E_ + i]; }
  else { src = i - E_; dst = src; }
  int pos = offs[b*(N_+1) + dst] + atomicAdd(&cursor[b*N_ + dst], 1);
  srcs[b*ET_ + pos] = (unsigned short)src;
}

// split + transpose W[K,NC] -> Wt[NC,K] (hi,lo)
__global__ void k_splitT(const float* __restrict__ w, short* __restrict__ hit,
                         short* __restrict__ lot, int K, int NC){
  int idx = blockIdx.x*256 + threadIdx.x;
  if (idx >= K*NC) return;
  int nn = idx / K, kk = idx - nn*K;
  float f = w[(size_t)kk*NC + nn];
  short h, l; split2(f, h, l);
  hit[idx] = h; lot[idx] = l;
}

// ---------------- BIG split-bf16 MFMA GEMM + fused attn epilogue ----------------
// BM=BN=128, 256 threads (2x2 waves of 64x64 each; M_rep=N_rep=4).
// 49 FLOP per LDS-read-byte -> MFMA-bound instead of LDS-port-bound.
// One wave covers a full 64-col head -> plain stores for a_s/a_d (no atomics).
template<int K, bool AFP32, int H>
__global__ __launch_bounds__(256,1) void k_gemm_b(const float* __restrict__ Af,
    const short* __restrict__ Ah_, const short* __restrict__ Al_,
    const short* __restrict__ Bh_, const short* __restrict__ Bl_,
    unsigned short* __restrict__ Ob, int NC,
    const float* __restrict__ atts, const float* __restrict__ attd,
    float* __restrict__ a_s, float* __restrict__ a_d){
  __shared__ short tAh[128][32], tAl[128][32], tBh[128][32], tBl[128][32];
  int t = threadIdx.x;
  int m0 = blockIdx.x*128, n0 = blockIdx.y*128;
  int w = t >> 6, l = t & 63;
  int wrow = w >> 1, wcol = w & 1, g = l >> 4, li = l & 15;
  // staging role: thread covers rows sr and sr+64, 16B k-chunk sq (4 lanes/row run = 64B)
  int sr = t >> 2, sq = t & 3;

  s16x8 sAh[2], sAl[2], sBh[2], sBl[2];
  auto stageLoad = [&](int k0){
    #pragma unroll
    for (int hh=0; hh<2; hh++){
      int r = sr + hh*64;
      if constexpr (AFP32){
        const float* ap = &Af[(size_t)(m0+r)*K + k0 + sq*8];
        float4 f0 = *reinterpret_cast<const float4*>(ap);
        float4 f1 = *reinterpret_cast<const float4*>(ap+4);
        float fv[8] = {f0.x,f0.y,f0.z,f0.w,f1.x,f1.y,f1.z,f1.w};
        #pragma unroll
        for (int j=0;j<8;j++){ short hi,lo; split2(fv[j],hi,lo); sAh[hh][j]=hi; sAl[hh][j]=lo; }
      } else {
        sAh[hh] = *reinterpret_cast<const s16x8*>(&Ah_[(size_t)(m0+r)*K + k0 + sq*8]);
        sAl[hh] = *reinterpret_cast<const s16x8*>(&Al_[(size_t)(m0+r)*K + k0 + sq*8]);
      }
      sBh[hh] = *reinterpret_cast<const s16x8*>(&Bh_[(size_t)(n0+r)*K + k0 + sq*8]);
      sBl[hh] = *reinterpret_cast<const s16x8*>(&Bl_[(size_t)(n0+r)*K + k0 + sq*8]);
    }
  };

  f32x4 acc[4][4];
  #pragma unroll
  for (int mi=0;mi<4;mi++)
    #pragma unroll
    for (int ni=0;ni<4;ni++) acc[mi][ni] = f32x4{0.f,0.f,0.f,0.f};

  int fcs = (g ^ ((li>>1)&3)) * 8;      // swizzled 16B chunk for frag reads

  stageLoad(0);
  for (int k0 = 0; k0 < K; k0 += 32){
    __syncthreads();                     // prev iter's frag reads complete
    #pragma unroll
    for (int hh=0; hh<2; hh++){
      int r = sr + hh*64;
      int cs = (sq ^ ((r>>1)&3)) * 8;
      *reinterpret_cast<s16x8*>(&tAh[r][cs]) = sAh[hh];
      *reinterpret_cast<s16x8*>(&tAl[r][cs]) = sAl[hh];
      *reinterpret_cast<s16x8*>(&tBh[r][cs]) = sBh[hh];
      *reinterpret_cast<s16x8*>(&tBl[r][cs]) = sBl[hh];
    }
    __syncthreads();
    if (k0 + 32 < K) stageLoad(k0 + 32); // global prefetch lands during MFMAs
    s16x8 ah[4], al[4], bh[4], bl[4];
    #pragma unroll
    for (int mi=0;mi<4;mi++){
      int rA = wrow*64 + mi*16 + li;
      ah[mi] = *reinterpret_cast<const s16x8*>(&tAh[rA][fcs]);
      al[mi] = *reinterpret_cast<const s16x8*>(&tAl[rA][fcs]);
    }
    #pragma unroll
    for (int ni=0;ni<4;ni++){
      int rB = wcol*64 + ni*16 + li;
      bh[ni] = *reinterpret_cast<const s16x8*>(&tBh[rB][fcs]);
      bl[ni] = *reinterpret_cast<const s16x8*>(&tBl[rB][fcs]);
    }
    #pragma unroll
    for (int mi=0;mi<4;mi++)
      #pragma unroll
      for (int ni=0;ni<4;ni++){
        acc[mi][ni] = mfma_bf16(ah[mi], bh[ni], acc[mi][ni]);
        acc[mi][ni] = mfma_bf16(ah[mi], bl[ni], acc[mi][ni]);
        acc[mi][ni] = mfma_bf16(al[mi], bh[ni], acc[mi][ni]);
      }
  }

  // C/D layout: col = lane&15, row = 4*(lane>>4) + reg
  int head = blockIdx.y*2 + wcol;        // one 64-col head per wave (NC=256)
  float attsv[4], attdv[4];
  #pragma unroll
  for (int ni=0;ni<4;ni++){
    int col = n0 + wcol*64 + ni*16 + li;
    attsv[ni] = atts[col]; attdv[ni] = attd[col];
  }
  #pragma unroll
  for (int mi=0;mi<4;mi++){
    #pragma unroll
    for (int j=0;j<4;j++){
      int row = m0 + wrow*64 + mi*16 + 4*g + j;
      float sa = acc[mi][0][j]*attsv[0] + acc[mi][1][j]*attsv[1]
               + acc[mi][2][j]*attsv[2] + acc[mi][3][j]*attsv[3];
      float sd = acc[mi][0][j]*attdv[0] + acc[mi][1][j]*attdv[1]
               + acc[mi][2][j]*attdv[2] + acc[mi][3][j]*attdv[3];
      #pragma unroll
      for (int m=1;m<16;m<<=1){ sa += __shfl_xor(sa,m,64); sd += __shfl_xor(sd,m,64); }
      if (li == 0){
        a_s[(size_t)row*H + head] = sa;   // single contributor -> plain store
        a_d[(size_t)row*H + head] = sd;
      }
      #pragma unroll
      for (int ni=0;ni<4;ni++){
        int col = n0 + wcol*64 + ni*16 + li;
        Ob[(size_t)row*NC + col] = f2bf(acc[mi][ni][j]);
      }
    }
  }
}

// ---------------- SMALL GEMM (layer 3, NC=64): round-7 kernel ----------------
template<int K, bool AFP32, int H>
__global__ __launch_bounds__(256) void k_gemm_s(const float* __restrict__ Af,
    const short* __restrict__ Ah, const short* __restrict__ Al,
    const short* __restrict__ Bh, const short* __restrict__ Bl,
    unsigned short* __restrict__ Ob, int NC,
    const float* __restrict__ atts, const float* __restrict__ attd,
    float* __restrict__ a_s, float* __restrict__ a_d){
  __shared__ short tAh[64][32], tAl[64][32], tBh[64][32], tBl[64][32];
  int t = threadIdx.x;
  int m0 = blockIdx.x*64, n0 = blockIdx.y*64;
  int head = blockIdx.y;
  int r = t >> 2, c = t & 3;
  int cs = (c ^ ((r >> 1) & 3)) * 8;
  int w = t >> 6, l = t & 63;
  int wr = w >> 1, wc = w & 1, g = l >> 4, li = l & 15;
  int rA = wr*32 + li, rB = wc*32 + li;
  int cA = (g ^ ((rA >> 1) & 3)) * 8;
  int cB = (g ^ ((rB >> 1) & 3)) * 8;
  f32x4 z = {0.f,0.f,0.f,0.f};
  f32x4 acc00=z, acc01=z, acc10=z, acc11=z;

  s16x8 vah, vaL, vbh, vbl;
  auto loadSlice = [&](int k0){
    vah = *reinterpret_cast<const s16x8*>(&Ah[(size_t)(m0+r)*K + k0 + c*8]);
    vaL = *reinterpret_cast<const s16x8*>(&Al[(size_t)(m0+r)*K + k0 + c*8]);
    vbh = *reinterpret_cast<const s16x8*>(&Bh[(size_t)(n0+r)*K + k0 + c*8]);
    vbl = *reinterpret_cast<const s16x8*>(&Bl[(size_t)(n0+r)*K + k0 + c*8]);
  };

  loadSlice(0);
  for (int k0 = 0; k0 < K; k0 += 32){
    __syncthreads();
    *reinterpret_cast<s16x8*>(&tAh[r][cs]) = vah;
    *reinterpret_cast<s16x8*>(&tAl[r][cs]) = vaL;
    *reinterpret_cast<s16x8*>(&tBh[r][cs]) = vbh;
    *reinterpret_cast<s16x8*>(&tBl[r][cs]) = vbl;
    __syncthreads();
    if (k0 + 32 < K) loadSlice(k0 + 32);
    s16x8 a0h = *reinterpret_cast<const s16x8*>(&tAh[rA   ][cA]);
    s16x8 a1h = *reinterpret_cast<const s16x8*>(&tAh[rA+16][cA]);
    s16x8 a0l = *reinterpret_cast<const s16x8*>(&tAl[rA   ][cA]);
    s16x8 a1l = *reinterpret_cast<const s16x8*>(&tAl[rA+16][cA]);
    s16x8 b0h = *reinterpret_cast<const s16x8*>(&tBh[rB   ][cB]);
    s16x8 b1h = *reinterpret_cast<const s16x8*>(&tBh[rB+16][cB]);
    s16x8 b0l = *reinterpret_cast<const s16x8*>(&tBl[rB   ][cB]);
    s16x8 b1l = *reinterpret_cast<const s16x8*>(&tBl[rB+16][cB]);
    acc00 = mfma_bf16(a0h, b0h, acc00);
    acc00 = mfma_bf16(a0h, b0l, acc00);
    acc00 = mfma_bf16(a0l, b0h, acc00);
    acc01 = mfma_bf16(a0h, b1h, acc01);
    acc01 = mfma_bf16(a0h, b1l, acc01);
    acc01 = mfma_bf16(a0l, b1h, acc01);
    acc10 = mfma_bf16(a1h, b0h, acc10);
    acc10 = mfma_bf16(a1h, b0l, acc10);
    acc10 = mfma_bf16(a1l, b0h, acc10);
    acc11 = mfma_bf16(a1h, b1h, acc11);
    acc11 = mfma_bf16(a1h, b1l, acc11);
    acc11 = mfma_bf16(a1l, b1h, acc11);
  }
  f32x4 accs[2][2] = {{acc00, acc01},{acc10, acc11}};
  float attsv[2], attdv[2];
  #pragma unroll
  for (int ni=0; ni<2; ni++){
    int colg = n0 + wc*32 + ni*16 + li;
    attsv[ni] = atts[colg];
    attdv[ni] = attd[colg];
  }
  #pragma unroll
  for (int mi=0; mi<2; mi++){
    #pragma unroll
    for (int j=0; j<4; j++){
      int row = m0 + wr*32 + mi*16 + 4*g + j;
      float sa = accs[mi][0][j]*attsv[0] + accs[mi][1][j]*attsv[1];
      float sd = accs[mi][0][j]*attdv[0] + accs[mi][1][j]*attdv[1];
      #pragma unroll
      for (int m=1; m<16; m<<=1){ sa += __shfl_xor(sa,m,64); sd += __shfl_xor(sd,m,64); }
      if (li == 0){
        atomicAdd(&a_s[(size_t)row*H + head], sa);
        atomicAdd(&a_d[(size_t)row*H + head], sd);
      }
      #pragma unroll
      for (int ni=0; ni<2; ni++){
        int col = n0 + wc*32 + ni*16 + li;
        Ob[(size_t)row*NC + col] = f2bf(accs[mi][ni][j]);
      }
    }
  }
}

// ---------------- pull-mode edge-softmax aggregation (multi-edge waves) ----------------
template<int HD, int H, bool ELU, bool SPLIT>
__global__ __launch_bounds__(256) void k_aggr(const unsigned short* __restrict__ h,
    const float* __restrict__ a_s, const float* __restrict__ a_d,
    const unsigned short* __restrict__ srcs, const int* __restrict__ offs,
    const float* __restrict__ bias, float* __restrict__ outf,
    short* __restrict__ outh, short* __restrict__ outl){
  constexpr int EPW = (HD==256) ? 2 : 4;   // edges per wave
  constexpr int LPE = 64/EPW;              // lanes per edge: 32 or 16
  constexpr int CPL = HD/LPE;              // cols per lane: 8 or 4
  constexpr int NP  = 4*EPW;               // edge slots per block: 8 or 16
  __shared__ float accL[NP][HD];
  __shared__ float psumL[NP][H];
  int ng = blockIdx.x;                     // b*N + n
  int b = ng >> 12, n = ng & (N_-1);
  int t = threadIdx.x;
  int w = t >> 6, l = t & 63;
  int sub = l / LPE, hl = l % LPE;
  int slot = w*EPW + sub;
  int st = offs[b*(N_+1)+n], en = offs[b*(N_+1)+n+1];
  const unsigned short* sp = &srcs[(size_t)b*ET_];
  const unsigned short* hb = &h[(size_t)b*N_*HD];
  const float* asb = &a_s[(size_t)b*N_*H];
  int head = (H==4) ? ((hl*CPL) >> 6) : 0;
  float adv = a_d[(size_t)ng*H + head];
  float acc[CPL];
  #pragma unroll
  for (int j=0;j<CPL;j++) acc[j]=0.f;
  float psum = 0.f;

  auto ldh = [&](int s, float* dst){
    const unsigned short* p = &hb[(size_t)s*HD + hl*CPL];
    if constexpr (CPL==8){
      uint4 q = *reinterpret_cast<const uint4*>(p);
      dst[0]=bflo(q.x); dst[1]=bfhi(q.x); dst[2]=bflo(q.y); dst[3]=bfhi(q.y);
      dst[4]=bflo(q.z); dst[5]=bfhi(q.z); dst[6]=bflo(q.w); dst[7]=bfhi(q.w);
    } else {
      uint2 q = *reinterpret_cast<const uint2*>(p);
      dst[0]=bflo(q.x); dst[1]=bfhi(q.x); dst[2]=bflo(q.y); dst[3]=bfhi(q.y);
    }
  };

  int i  = st + slot;
  int s0 = (i      < en) ? (int)sp[i]      : 0;
  int s1 = (i+NP   < en) ? (int)sp[i+NP]   : 0;
  float hv[CPL], hn[CPL], asv, asn;
  ldh(s0, hv); asv = asb[s0*H + head];

  while (i < en){
    int s2 = (i+2*NP < en) ? (int)sp[i+2*NP] : 0;   // prefetch 2 ahead
    ldh(s1, hn); asn = asb[s1*H + head];            // issue next slot loads
    float e = asv + adv;                            // compute current edge
    e = fmaxf(e, 0.2f*e);                           // leaky_relu
    float p = __expf(e);
    #pragma unroll
    for (int j=0;j<CPL;j++) acc[j] = fmaf(p, hv[j], acc[j]);
    psum += p;
    #pragma unroll
    for (int j=0;j<CPL;j++) hv[j] = hn[j];
    asv = asn; s1 = s2; i += NP;
  }

  #pragma unroll
  for (int j=0;j<CPL;j+=4)
    *reinterpret_cast<float4*>(&accL[slot][hl*CPL+j]) =
        make_float4(acc[j],acc[j+1],acc[j+2],acc[j+3]);
  if constexpr (H==4){ if ((hl & 7)==0) psumL[slot][hl>>3] = psum; }
  else               { if (hl == 0)     psumL[slot][0]     = psum; }
  __syncthreads();
  if (t < HD){
    float a = 0.f;
    #pragma unroll
    for (int k=0;k<NP;k++) a += accL[k][t];
    int h2 = (H==4) ? (t>>6) : 0;
    float ps = 0.f;
    #pragma unroll
    for (int k=0;k<NP;k++) ps += psumL[k][h2];
    float val = a/(ps + 1e-16f) + bias[t];
    if (ELU) val = val > 0.f ? val : expm1f(val);
    size_t idx = (size_t)ng*HD + t;
    if (SPLIT){ short hh, ll; split2(val, hh, ll); outh[idx]=hh; outl[idx]=ll; }
    else outf[idx] = val;
  }
}

// ---------------- node-mean reduction ----------------
__global__ void k_reduce(const float* __restrict__ x3, float* __restrict__ embed){
  __shared__ float red[256];
  int bid = blockIdx.x; int b = bid>>4, chunk = bid & 15;
  int t = threadIdx.x; int col = t & 63, q = t>>6;
  float s = 0.f;
  int r0 = chunk*256 + q*64;
  const float* p = &x3[((size_t)b*N_ + r0)*64 + col];
  for (int j=0;j<64;j++) s += p[(size_t)j*64];
  red[t]=s; __syncthreads();
  if (t<64){
    float v = red[t]+red[t+64]+red[t+128]+red[t+192];
    atomicAdd(&embed[b*64+t], v);
  }
}

// ---------------- classifier + log_softmax + loss + argmax ----------------
__global__ void k_final(const float* __restrict__ embed, const float* __restrict__ Wc,
                        const float* __restrict__ bc, const int* __restrict__ labels,
                        float* __restrict__ out){
  __shared__ float lg[B_][C_];
  __shared__ float lossv[B_];
  int t = threadIdx.x;
  if (t < B_*C_){
    int b = t / C_, c = t - b*C_;
    float s = 0.f;
    for (int k=0;k<64;k++) s += embed[b*64+k]*Wc[k*C_+c];
    lg[b][c] = s*(1.0f/N_) + bc[c];
  }
  __syncthreads();
  if (t < B_){
    int b = t;
    float mx = lg[b][0]; int pred = 0;
    for (int c=1;c<C_;c++) if (lg[b][c] > mx){ mx = lg[b][c]; pred = c; }
    float se = 0.f;
    for (int c=0;c<C_;c++) se += expf(lg[b][c]-mx);
    float lse = mx + logf(se);
    int lab = labels[b];
    lossv[b] = lse - lg[b][lab];
    out[b]      = (float)pred;
    out[B_+b]   = (float)lab;
  }
  __syncthreads();
  if (t==0) out[8] = 0.25f*(lossv[0]+lossv[1]+lossv[2]+lossv[3]);
}

extern "C" void kernel_launch(void* const* d_in, const int* in_sizes, int n_in,
                              void* d_out, int out_size, void* d_ws, size_t ws_size,
                              hipStream_t stream){
  const float* x0     = (const float*)d_in[0];
  const int*   labels = (const int*)d_in[1];
  const int*   ei     = (const int*)d_in[2];
  const float* W1=(const float*)d_in[3],  *as1=(const float*)d_in[4],
             *ad1=(const float*)d_in[5],  *b1 =(const float*)d_in[6];
  const float* W2=(const float*)d_in[7],  *as2=(const float*)d_in[8],
             *ad2=(const float*)d_in[9],  *b2 =(const float*)d_in[10];
  const float* W3=(const float*)d_in[11], *as3=(const float*)d_in[12],
             *ad3=(const float*)d_in[13], *b3 =(const float*)d_in[14];
  const float* Wc=(const float*)d_in[15], *bc =(const float*)d_in[16];
  float* out = (float*)d_out;

  char* ws = (char*)d_ws;
  size_t off = 0;
  auto alloc = [&](size_t bytes)->void*{ void* p = ws + off; off += (bytes + 255) & ~(size_t)255; return p; };
  unsigned short* hbuf = (unsigned short*)alloc((size_t)B_*N_*HD_*2); // GEMM out, bf16
  float* xcur3  = (float*)alloc((size_t)B_*N_*64*4);     // layer-3 aggr out (fp32)
  int*   counts = (int*)alloc((size_t)B_*N_*4);
  int*   cursor = (int*)alloc((size_t)B_*N_*4);
  int*   offs   = (int*)alloc((size_t)B_*(N_+1)*4);
  unsigned short* srcs = (unsigned short*)alloc((size_t)B_*ET_*2);
  float* embed  = (float*)alloc((size_t)B_*64*4);
  float* a_s1   = (float*)alloc((size_t)B_*N_*H_*4);     // zeroed block start
  float* a_d1   = (float*)alloc((size_t)B_*N_*H_*4);
  float* a_s2   = (float*)alloc((size_t)B_*N_*H_*4);
  float* a_d2   = (float*)alloc((size_t)B_*N_*H_*4);
  float* a_s3   = (float*)alloc((size_t)B_*N_*4);
  float* a_d3   = (float*)alloc((size_t)B_*N_*4);
  size_t zend   = off;                                   // zeroed block end
  short* Ah     = (short*)alloc((size_t)B_*N_*HD_*2);    // split aggr out (layers 2-3 A)
  short* Al     = (short*)alloc((size_t)B_*N_*HD_*2);
  short* Wht    = (short*)alloc((size_t)768*256*2);      // split W^T (max)
  short* Wlt    = (short*)alloc((size_t)768*256*2);

  hipMemsetAsync(counts, 0, (size_t)B_*N_*4*2, stream);            // counts+cursor
  hipMemsetAsync(embed,  0, zend - ((char*)embed - ws), stream);   // embed + a_s/a_d x3

  int nb = (B_*ET_ + 255)/256;
  k_count  <<<nb, 256, 0, stream>>>(ei, counts);
  k_scan   <<<B_, 1024, 0, stream>>>(counts, offs);
  k_scatter<<<nb, 256, 0, stream>>>(ei, offs, cursor, srcs);

  // ---- layer 1: 768 -> 4x64, concat, elu (A = x0 fp32, split in staging) ----
  {
    k_splitT<<<(768*256+255)/256, 256, 0, stream>>>(W1, Wht, Wlt, 768, 256);
    k_gemm_b<768,true,4><<<dim3(B_*N_/128, 2), 256, 0, stream>>>(x0, nullptr, nullptr,
        Wht, Wlt, hbuf, 256, as1, ad1, a_s1, a_d1);
    k_aggr<256,4,true,true><<<B_*N_, 256, 0, stream>>>(hbuf, a_s1, a_d1, srcs, offs, b1,
                                                       nullptr, Ah, Al);
  }
  // ---- layer 2: 256 -> 4x64, concat, elu ----
  {
    k_splitT<<<(256*256+255)/256, 256, 0, stream>>>(W2, Wht, Wlt, 256, 256);
    k_gemm_b<256,false,4><<<dim3(B_*N_/128, 2), 256, 0, stream>>>(nullptr, Ah, Al,
        Wht, Wlt, hbuf, 256, as2, ad2, a_s2, a_d2);
    k_aggr<256,4,true,true><<<B_*N_, 256, 0, stream>>>(hbuf, a_s2, a_d2, srcs, offs, b2,
                                                       nullptr, Ah, Al);
  }
  // ---- layer 3: 256 -> 64, 1 head, mean(=identity), no elu ----
  {
    k_splitT<<<(256*64+255)/256, 256, 0, stream>>>(W3, Wht, Wlt, 256, 64);
    k_gemm_s<256,false,1><<<dim3(B_*N_/64, 1), 256, 0, stream>>>(nullptr, Ah, Al,
        Wht, Wlt, hbuf, 64, as3, ad3, a_s3, a_d3);
    k_aggr<64,1,false,false><<<B_*N_, 256, 0, stream>>>(hbuf, a_s3, a_d3, srcs, offs, b3,
                                                        xcur3, nullptr, nullptr);
  }

  k_reduce<<<B_*16, 256, 0, stream>>>(xcur3, embed);
  k_final <<<1, 64, 0, stream>>>(embed, Wc, bc, labels, out);
}